// Round 3
// baseline (1582.706 us; speedup 1.0000x reference)
//
#include <hip/hip_runtime.h>

// Problem dims (fixed by the reference)
#define T_TOK 2048      // B*S tokens
#define H_DIM 2048
#define E_NUM 32
#define I_DIM 1024
#define IS_DIM 2048
#define K_TOT (E_NUM * I_DIM + IS_DIM)   // 34816 = routed(32768) + shared(2048)
#define SLOT_CAP 2040   // per-expert token-slot capacity (fits old DW region)

typedef __bf16 bf16x8 __attribute__((ext_vector_type(8)));
typedef float  f32x4  __attribute__((ext_vector_type(4)));
static_assert(sizeof(bf16x8) == 16, "bf16x8 must be 16B");

// Workspace layout (bytes). Total = 579,076,096 (~552 MiB) — unchanged.
// [0,128)            cnt[32] int (zeroed per launch)
// [128, 262144)      pairs[E][SLOT_CAP] uint  (hi16 = bf16 weight, lo16 = token)
#define OFF_CNT   ((size_t)0)
#define OFF_PAIRS ((size_t)128)
#define OFF_XB    ((size_t)262144)      // xb       [T,H] bf16        8,388,608
#define OFF_WGT   ((size_t)8650752)     // wgT [E][I][H] bf16       134,217,728
#define OFF_WUT   ((size_t)142868480)   // wuT [E][I][H] bf16       134,217,728
#define OFF_WSGT  ((size_t)277086208)   // wsgT [IS][H] bf16          8,388,608
#define OFF_WSUT  ((size_t)285474816)   // wsuT [IS][H] bf16          8,388,608
#define OFF_WDT   ((size_t)293863424)   // wdT [H][K_TOT] bf16      142,606,336
#define OFF_H     ((size_t)436469760)   // h   [T][K_TOT] bf16      142,606,336

__device__ __forceinline__ unsigned short f2bf(float f) {
  unsigned int u = __float_as_uint(f);
  u += 0x7fffu + ((u >> 16) & 1u);   // round-to-nearest-even
  return (unsigned short)(u >> 16);
}

__device__ __forceinline__ void gld16(const void* g, void* l) {
  __builtin_amdgcn_global_load_lds(
      (const __attribute__((address_space(1))) unsigned int*)g,
      (__attribute__((address_space(3))) unsigned int*)l, 16, 0, 0);
}

// ---------------------------------------------------------------------------
// Router: scores = sigmoid(x @ gw^T); top-8; renorm; *2.5.
// Emits per-expert (weight,token) pair lists + counts (atomic append).
// ---------------------------------------------------------------------------
__global__ __launch_bounds__(256) void router_kernel(
    const float* __restrict__ x, const float* __restrict__ gw,
    int* __restrict__ cnt, unsigned int* __restrict__ pairs)
{
  const int t = blockIdx.x;
  __shared__ float xs[H_DIM];
  __shared__ float sc[E_NUM];
  const float4* xr = (const float4*)(x + (long)t * H_DIM);
  for (int i = threadIdx.x; i < H_DIM / 4; i += 256) ((float4*)xs)[i] = xr[i];
  __syncthreads();
  const int e = threadIdx.x >> 3, p = threadIdx.x & 7;
  const float4* ga = (const float4*)(gw + (long)e * H_DIM);
  const float4* xa = (const float4*)xs;
  float s = 0.f;
  #pragma unroll 4
  for (int i = p * 64; i < p * 64 + 64; ++i) {
    float4 a = ga[i], b = xa[i];
    s += a.x * b.x + a.y * b.y + a.z * b.z + a.w * b.w;
  }
  s += __shfl_down(s, 4, 8);
  s += __shfl_down(s, 2, 8);
  s += __shfl_down(s, 1, 8);
  if (p == 0) sc[e] = 1.f / (1.f + expf(-s));
  __syncthreads();
  if (threadIdx.x == 0) {
    float v[E_NUM];
    #pragma unroll
    for (int i = 0; i < E_NUM; ++i) v[i] = sc[i];
    unsigned mask = 0; float sum = 0.f;
    int sel[8]; float wv[8];
    for (int k = 0; k < 8; ++k) {
      float best = -1.f; int bi = 0;
      for (int i = 0; i < E_NUM; ++i)
        if (!((mask >> i) & 1u) && v[i] > best) { best = v[i]; bi = i; }
      mask |= 1u << bi; sel[k] = bi; wv[k] = best; sum += best;
    }
    const float scale = 2.5f / (sum + 1e-20f);
    for (int k = 0; k < 8; ++k) {
      const int slot = atomicAdd(&cnt[sel[k]], 1);
      if (slot < SLOT_CAP) {
        const unsigned int w16 = (unsigned int)f2bf(wv[k] * scale);
        pairs[sel[k] * SLOT_CAP + slot] = (w16 << 16) | (unsigned int)t;
      }
    }
  }
}

// ---------------------------------------------------------------------------
// fp32 -> bf16 elementwise (x -> xb)
// ---------------------------------------------------------------------------
__global__ __launch_bounds__(256) void cvt_bf16_kernel(
    const float* __restrict__ in, unsigned short* __restrict__ out, int n4)
{
  int i = blockIdx.x * 256 + threadIdx.x;
  if (i >= n4) return;
  float4 v = ((const float4*)in)[i];
  ushort4 o;
  o.x = f2bf(v.x); o.y = f2bf(v.y); o.z = f2bf(v.z); o.w = f2bf(v.w);
  ((ushort4*)out)[i] = o;
}

// ---------------------------------------------------------------------------
// Transpose + fp32->bf16: in fp32 [R][C] (row-major, ldin=C) -> out bf16 [C][R]
// with out row stride ldout; batched over blockIdx.z.
// ---------------------------------------------------------------------------
__global__ __launch_bounds__(256) void transpose_cvt(
    const float* __restrict__ in, unsigned short* __restrict__ out,
    int R, int C, int ldout, long in_bs, long out_bs)
{
  in  += (long)blockIdx.z * in_bs;
  out += (long)blockIdx.z * out_bs;
  __shared__ float tile[64][65];
  const int c0 = blockIdx.x * 64;
  const int r0 = blockIdx.y * 64;
  const int t = threadIdx.x;
  const int lr = t >> 4;
  const int lc = (t & 15) << 2;
  #pragma unroll
  for (int rr = 0; rr < 64; rr += 16) {
    float4 v = *(const float4*)(in + (long)(r0 + lr + rr) * C + c0 + lc);
    tile[lr + rr][lc + 0] = v.x;
    tile[lr + rr][lc + 1] = v.y;
    tile[lr + rr][lc + 2] = v.z;
    tile[lr + rr][lc + 3] = v.w;
  }
  __syncthreads();
  #pragma unroll
  for (int rr = 0; rr < 64; rr += 16) {
    const int c = c0 + lr + rr;
    ushort4 o;
    o.x = f2bf(tile[lc + 0][lr + rr]);
    o.y = f2bf(tile[lc + 1][lr + rr]);
    o.z = f2bf(tile[lc + 2][lr + rr]);
    o.w = f2bf(tile[lc + 3][lr + rr]);
    *(ushort4*)(out + (long)c * ldout + r0 + lc) = o;
  }
}

// ---------------------------------------------------------------------------
// Sparse (top-8 gathered) gate+up GEMM + silu(g)*u*w epilogue -> h scatter.
// A rows gathered from xb via per-expert token list; only slots < cnt[e] are
// computed/written. XOR-swizzled LDS (T2/m173): linear gld16 dest, pre-swizzled
// global source, XOR on ds_read.
// Block: 256 thr (4 waves 2x2), tile 128(slots) x 64(N of I), BK=64.
// ---------------------------------------------------------------------------
__global__ __launch_bounds__(256) void gate_up_moe_kernel(
    const unsigned short* __restrict__ xb,
    const unsigned short* __restrict__ bgT,
    const unsigned short* __restrict__ buT,
    const int* __restrict__ cnt,
    const unsigned int* __restrict__ pairs,
    unsigned short* __restrict__ hout)
{
  const int e = blockIdx.z;
  const int cnte = cnt[e];
  const int m0 = blockIdx.x * 128;
  if (m0 >= cnte) return;
  const int n0 = blockIdx.y * 64;
  const unsigned short* Bg = bgT + ((long)e * I_DIM + n0) * H_DIM;
  const unsigned short* Bu = buT + ((long)e * I_DIM + n0) * H_DIM;

  __shared__ unsigned short sA[128 * 64];
  __shared__ unsigned short sBg[64 * 64];
  __shared__ unsigned short sBu[64 * 64];

  const int tid = threadIdx.x;
  const int lane = tid & 63;
  const int wid = tid >> 6;
  const int wm = wid >> 1, wn = wid & 1;
  const int l15 = lane & 15;
  const int lk  = (lane >> 4) * 8;
  const int srow = tid >> 3;                       // staging row within 32-group
  const int scol = (tid & 7) * 8;                  // linear LDS dest chunk
  const int scolsw = (((tid & 7) ^ ((tid >> 3) & 7))) * 8;  // pre-swizzled src
  const int ksw = (l15 & 7) << 3;                  // read-side XOR

  // gathered A source rows (4 staging rows per thread), safe base for tails
  const unsigned short* asrc[4];
  #pragma unroll
  for (int r = 0; r < 4; ++r) {
    const int slot = m0 + r * 32 + srow;
    const unsigned int pr = (slot < cnte) ? pairs[e * SLOT_CAP + slot] : 0u;
    asrc[r] = xb + (long)(pr & 0xFFFFu) * H_DIM + scolsw;
  }

  const f32x4 fz = {0.f, 0.f, 0.f, 0.f};
  f32x4 accg[4][2], accu[4][2];
  #pragma unroll
  for (int i = 0; i < 4; ++i)
    #pragma unroll
    for (int j = 0; j < 2; ++j) { accg[i][j] = fz; accu[i][j] = fz; }

  for (int k0 = 0; k0 < H_DIM; k0 += 64) {
    #pragma unroll
    for (int r = 0; r < 4; ++r)
      gld16(asrc[r] + k0, sA + (r * 32 + srow) * 64 + scol);
    #pragma unroll
    for (int r = 0; r < 2; ++r) {
      gld16(Bg + (long)(r * 32 + srow) * H_DIM + k0 + scolsw,
            sBg + (r * 32 + srow) * 64 + scol);
      gld16(Bu + (long)(r * 32 + srow) * H_DIM + k0 + scolsw,
            sBu + (r * 32 + srow) * 64 + scol);
    }
    __syncthreads();
    #pragma unroll
    for (int kk = 0; kk < 2; ++kk) {
      const int ko = kk * 32 + lk;
      bf16x8 a[4], g[2], u[2];
      #pragma unroll
      for (int mi = 0; mi < 4; ++mi)
        a[mi] = *(const bf16x8*)(sA + (wm * 64 + mi * 16 + l15) * 64 + (ko ^ ksw));
      #pragma unroll
      for (int ni = 0; ni < 2; ++ni) {
        g[ni] = *(const bf16x8*)(sBg + (wn * 32 + ni * 16 + l15) * 64 + (ko ^ ksw));
        u[ni] = *(const bf16x8*)(sBu + (wn * 32 + ni * 16 + l15) * 64 + (ko ^ ksw));
      }
      #pragma unroll
      for (int mi = 0; mi < 4; ++mi)
        #pragma unroll
        for (int ni = 0; ni < 2; ++ni) {
          accg[mi][ni] = __builtin_amdgcn_mfma_f32_16x16x32_bf16(a[mi], g[ni], accg[mi][ni], 0, 0, 0);
          accu[mi][ni] = __builtin_amdgcn_mfma_f32_16x16x32_bf16(a[mi], u[ni], accu[mi][ni], 0, 0, 0);
        }
    }
    __syncthreads();
  }

  const int colb = e * I_DIM + n0 + wn * 32;
  #pragma unroll
  for (int mi = 0; mi < 4; ++mi) {
    #pragma unroll
    for (int r = 0; r < 4; ++r) {
      const int slot = m0 + wm * 64 + mi * 16 + (lane >> 4) * 4 + r;
      if (slot < cnte) {
        const unsigned int pr = pairs[e * SLOT_CAP + slot];
        const int tok = (int)(pr & 0xFFFFu);
        const float w = __uint_as_float(pr & 0xFFFF0000u);
        #pragma unroll
        for (int ni = 0; ni < 2; ++ni) {
          const float gv = accg[mi][ni][r];
          const float uv = accu[mi][ni][r];
          const float sv = (gv / (1.f + expf(-gv))) * uv * w;
          hout[(long)tok * K_TOT + colb + ni * 16 + l15] = f2bf(sv);
        }
      }
    }
  }
}

// ---------------------------------------------------------------------------
// Dense gate+up GEMM for the shared expert (weight 1). Same swizzled m97 core.
// ---------------------------------------------------------------------------
__global__ __launch_bounds__(256) void gate_up_kernel(
    const unsigned short* __restrict__ xb,
    const unsigned short* __restrict__ bgT,
    const unsigned short* __restrict__ buT,
    unsigned short* __restrict__ hout,
    int Ncols, int col_off)
{
  const int t0 = blockIdx.x * 128;
  const int n0 = blockIdx.y * 64;
  const unsigned short* Bg = bgT + (long)n0 * H_DIM;
  const unsigned short* Bu = buT + (long)n0 * H_DIM;
  const unsigned short* A  = xb + (long)t0 * H_DIM;

  __shared__ unsigned short sA[128 * 64];
  __shared__ unsigned short sBg[64 * 64];
  __shared__ unsigned short sBu[64 * 64];

  const int tid = threadIdx.x;
  const int lane = tid & 63;
  const int wid = tid >> 6;
  const int wm = wid >> 1, wn = wid & 1;
  const int l15 = lane & 15;
  const int lk  = (lane >> 4) * 8;
  const int srow = tid >> 3;
  const int scol = (tid & 7) * 8;
  const int scolsw = (((tid & 7) ^ ((tid >> 3) & 7))) * 8;
  const int ksw = (l15 & 7) << 3;

  const f32x4 fz = {0.f, 0.f, 0.f, 0.f};
  f32x4 accg[4][2], accu[4][2];
  #pragma unroll
  for (int i = 0; i < 4; ++i)
    #pragma unroll
    for (int j = 0; j < 2; ++j) { accg[i][j] = fz; accu[i][j] = fz; }

  for (int k0 = 0; k0 < H_DIM; k0 += 64) {
    #pragma unroll
    for (int r = 0; r < 4; ++r)
      gld16(A + (long)(r * 32 + srow) * H_DIM + k0 + scolsw,
            sA + (r * 32 + srow) * 64 + scol);
    #pragma unroll
    for (int r = 0; r < 2; ++r) {
      gld16(Bg + (long)(r * 32 + srow) * H_DIM + k0 + scolsw,
            sBg + (r * 32 + srow) * 64 + scol);
      gld16(Bu + (long)(r * 32 + srow) * H_DIM + k0 + scolsw,
            sBu + (r * 32 + srow) * 64 + scol);
    }
    __syncthreads();
    #pragma unroll
    for (int kk = 0; kk < 2; ++kk) {
      const int ko = kk * 32 + lk;
      bf16x8 a[4], g[2], u[2];
      #pragma unroll
      for (int mi = 0; mi < 4; ++mi)
        a[mi] = *(const bf16x8*)(sA + (wm * 64 + mi * 16 + l15) * 64 + (ko ^ ksw));
      #pragma unroll
      for (int ni = 0; ni < 2; ++ni) {
        g[ni] = *(const bf16x8*)(sBg + (wn * 32 + ni * 16 + l15) * 64 + (ko ^ ksw));
        u[ni] = *(const bf16x8*)(sBu + (wn * 32 + ni * 16 + l15) * 64 + (ko ^ ksw));
      }
      #pragma unroll
      for (int mi = 0; mi < 4; ++mi)
        #pragma unroll
        for (int ni = 0; ni < 2; ++ni) {
          accg[mi][ni] = __builtin_amdgcn_mfma_f32_16x16x32_bf16(a[mi], g[ni], accg[mi][ni], 0, 0, 0);
          accu[mi][ni] = __builtin_amdgcn_mfma_f32_16x16x32_bf16(a[mi], u[ni], accu[mi][ni], 0, 0, 0);
        }
    }
    __syncthreads();
  }

  const int colb = col_off + n0 + wn * 32;
  #pragma unroll
  for (int mi = 0; mi < 4; ++mi) {
    #pragma unroll
    for (int r = 0; r < 4; ++r) {
      const int t = t0 + wm * 64 + mi * 16 + (lane >> 4) * 4 + r;
      #pragma unroll
      for (int ni = 0; ni < 2; ++ni) {
        const float gv = accg[mi][ni][r];
        const float uv = accu[mi][ni][r];
        const float sv = (gv / (1.f + expf(-gv))) * uv;
        hout[(long)t * K_TOT + colb + ni * 16 + l15] = f2bf(sv);
      }
    }
  }
}

// ---------------------------------------------------------------------------
// Down GEMM + combine: out[T,H] = h[T,K_TOT] @ wdT^T  (wdT is [H][K_TOT] bf16)
// Block: 256 thr, tile 128(M) x 64(N), BK=64; fp32 output. Same XOR swizzle.
// ---------------------------------------------------------------------------
__global__ __launch_bounds__(256) void down_kernel(
    const unsigned short* __restrict__ hbuf,
    const unsigned short* __restrict__ wdT,
    float* __restrict__ out)
{
  const int t0 = blockIdx.x * 128;
  const int n0 = blockIdx.y * 64;
  const unsigned short* A = hbuf + (long)t0 * K_TOT;
  const unsigned short* B = wdT + (long)n0 * K_TOT;

  __shared__ unsigned short sA[128 * 64];
  __shared__ unsigned short sB[64 * 64];

  const int tid = threadIdx.x;
  const int lane = tid & 63;
  const int wid = tid >> 6;
  const int wm = wid >> 1, wn = wid & 1;
  const int l15 = lane & 15;
  const int lk  = (lane >> 4) * 8;
  const int srow = tid >> 3;
  const int scol = (tid & 7) * 8;
  const int scolsw = (((tid & 7) ^ ((tid >> 3) & 7))) * 8;
  const int ksw = (l15 & 7) << 3;

  const f32x4 fz = {0.f, 0.f, 0.f, 0.f};
  f32x4 acc[4][2];
  #pragma unroll
  for (int i = 0; i < 4; ++i)
    #pragma unroll
    for (int j = 0; j < 2; ++j) acc[i][j] = fz;

  for (long k0 = 0; k0 < K_TOT; k0 += 64) {
    #pragma unroll
    for (int r = 0; r < 4; ++r)
      gld16(A + (long)(r * 32 + srow) * K_TOT + k0 + scolsw,
            sA + (r * 32 + srow) * 64 + scol);
    #pragma unroll
    for (int r = 0; r < 2; ++r)
      gld16(B + (long)(r * 32 + srow) * K_TOT + k0 + scolsw,
            sB + (r * 32 + srow) * 64 + scol);
    __syncthreads();
    #pragma unroll
    for (int kk = 0; kk < 2; ++kk) {
      const int ko = kk * 32 + lk;
      bf16x8 a[4], b[2];
      #pragma unroll
      for (int mi = 0; mi < 4; ++mi)
        a[mi] = *(const bf16x8*)(sA + (wm * 64 + mi * 16 + l15) * 64 + (ko ^ ksw));
      #pragma unroll
      for (int ni = 0; ni < 2; ++ni)
        b[ni] = *(const bf16x8*)(sB + (wn * 32 + ni * 16 + l15) * 64 + (ko ^ ksw));
      #pragma unroll
      for (int mi = 0; mi < 4; ++mi)
        #pragma unroll
        for (int ni = 0; ni < 2; ++ni)
          acc[mi][ni] = __builtin_amdgcn_mfma_f32_16x16x32_bf16(a[mi], b[ni], acc[mi][ni], 0, 0, 0);
    }
    __syncthreads();
  }

  #pragma unroll
  for (int mi = 0; mi < 4; ++mi) {
    #pragma unroll
    for (int r = 0; r < 4; ++r) {
      const int t = t0 + wm * 64 + mi * 16 + (lane >> 4) * 4 + r;
      #pragma unroll
      for (int ni = 0; ni < 2; ++ni) {
        const int col = n0 + wn * 32 + ni * 16 + l15;
        out[(long)t * H_DIM + col] = acc[mi][ni][r];
      }
    }
  }
}

// ---------------------------------------------------------------------------
extern "C" void kernel_launch(void* const* d_in, const int* in_sizes, int n_in,
                              void* d_out, int out_size, void* d_ws, size_t ws_size,
                              hipStream_t stream) {
  (void)in_sizes; (void)n_in; (void)out_size; (void)ws_size;
  const float* x   = (const float*)d_in[0];
  const float* gw  = (const float*)d_in[1];
  const float* wg  = (const float*)d_in[2];
  const float* wu  = (const float*)d_in[3];
  const float* wd  = (const float*)d_in[4];
  const float* wsg = (const float*)d_in[5];
  const float* wsu = (const float*)d_in[6];
  const float* wsd = (const float*)d_in[7];
  float* out = (float*)d_out;
  char* ws = (char*)d_ws;

  int*            cnt     = (int*)(ws + OFF_CNT);
  unsigned int*   pairs   = (unsigned int*)(ws + OFF_PAIRS);
  unsigned short* xb      = (unsigned short*)(ws + OFF_XB);
  unsigned short* wgT     = (unsigned short*)(ws + OFF_WGT);
  unsigned short* wuT     = (unsigned short*)(ws + OFF_WUT);
  unsigned short* wsgT    = (unsigned short*)(ws + OFF_WSGT);
  unsigned short* wsuT    = (unsigned short*)(ws + OFF_WSUT);
  unsigned short* wdT     = (unsigned short*)(ws + OFF_WDT);
  unsigned short* hbuf    = (unsigned short*)(ws + OFF_H);

  // zero the router counters and the h buffer (non-selected expert slots
  // must be exact zeros for the dense down-GEMM)
  hipMemsetAsync(ws + OFF_CNT, 0, 128, stream);
  hipMemsetAsync(ws + OFF_H, 0, (size_t)T_TOK * K_TOT * 2, stream);

  // router (emits per-expert token/weight lists) + activation convert
  router_kernel<<<T_TOK, 256, 0, stream>>>(x, gw, cnt, pairs);
  cvt_bf16_kernel<<<(T_TOK * H_DIM / 4 + 255) / 256, 256, 0, stream>>>(
      x, xb, T_TOK * H_DIM / 4);

  // weight transpose + bf16 convert
  transpose_cvt<<<dim3(16, 32, 32), 256, 0, stream>>>(
      wg, wgT, H_DIM, I_DIM, H_DIM, (long)H_DIM * I_DIM, (long)I_DIM * H_DIM);
  transpose_cvt<<<dim3(16, 32, 32), 256, 0, stream>>>(
      wu, wuT, H_DIM, I_DIM, H_DIM, (long)H_DIM * I_DIM, (long)I_DIM * H_DIM);
  transpose_cvt<<<dim3(32, 16, 32), 256, 0, stream>>>(
      wd, wdT, I_DIM, H_DIM, K_TOT, (long)I_DIM * H_DIM, (long)I_DIM);
  transpose_cvt<<<dim3(32, 32, 1), 256, 0, stream>>>(
      wsg, wsgT, H_DIM, IS_DIM, H_DIM, 0, 0);
  transpose_cvt<<<dim3(32, 32, 1), 256, 0, stream>>>(
      wsu, wsuT, H_DIM, IS_DIM, H_DIM, 0, 0);
  transpose_cvt<<<dim3(32, 32, 1), 256, 0, stream>>>(
      wsd, wdT + E_NUM * I_DIM, IS_DIM, H_DIM, K_TOT, 0, 0);

  // sparse top-8 gathered experts gate+up (router weight folded in)
  gate_up_moe_kernel<<<dim3(16, 16, 32), 256, 0, stream>>>(
      xb, wgT, wuT, cnt, pairs, hbuf);
  // shared expert gate+up (weight 1)
  gate_up_kernel<<<dim3(16, 32), 256, 0, stream>>>(
      xb, wsgT, wsuT, hbuf, IS_DIM, E_NUM * I_DIM);

  // single fused down-proj + combine + shared-down
  down_kernel<<<dim3(16, 32), 256, 0, stream>>>(hbuf, wdT, out);
}

// Round 4
// 969.998 us; speedup vs baseline: 1.6317x; 1.6317x over previous
//
#include <hip/hip_runtime.h>

// Problem dims (fixed by the reference)
#define T_TOK 2048      // B*S tokens
#define H_DIM 2048
#define E_NUM 32
#define I_DIM 1024
#define IS_DIM 2048
#define K_TOT (E_NUM * I_DIM + IS_DIM)   // 34816 = routed(32768) + shared(2048)
#define SLOT_CAP 2048   // per-expert token-slot capacity (cnt_e <= T <= 2048)
#define MAX_TILES 160   // sum ceil(cnt_e/128) <= 16384/128 + 32 = 160

typedef __bf16 bf16x8 __attribute__((ext_vector_type(8)));
typedef float  f32x4  __attribute__((ext_vector_type(4)));
static_assert(sizeof(bf16x8) == 16, "bf16x8 must be 16B");

// Workspace layout (bytes). Total = 570,688,512 (< 579,076,096 proven OK).
#define OFF_CNT   ((size_t)0)            // cnt[32] int                    128
#define OFF_NT    ((size_t)128)          // ntiles int                     4
#define OFF_TILES ((size_t)256)          // tiles[160] uint (e<<16|m0)     640
#define OFF_PAIRS ((size_t)1024)         // pairs[32][2048] uint       262,144
#define OFF_XB    ((size_t)263168)       // xb [T,H] bf16            8,388,608
#define OFF_WGT   ((size_t)8651776)      // wgT [E][I][H] bf16     134,217,728
#define OFF_WUT   ((size_t)142869504)    // wuT [E][I][H] bf16     134,217,728
                                         //   (hs[T][IS] bf16 ALIASES wuT[0:8MB];
                                         //    wuT is dead after gate_up_moe)
#define OFF_HS    OFF_WUT
#define OFF_WSGT  ((size_t)277087232)    // wsgT [IS][H] bf16        8,388,608
#define OFF_WSUT  ((size_t)285475840)    // wsuT [IS][H] bf16        8,388,608
#define OFF_WDT   ((size_t)293864448)    // wdT [H][K_TOT] bf16    142,606,336
#define OFF_ACT   ((size_t)436470784)    // act [32][2048][1024] bf16 134,217,728

__device__ __forceinline__ unsigned short f2bf(float f) {
  unsigned int u = __float_as_uint(f);
  u += 0x7fffu + ((u >> 16) & 1u);   // round-to-nearest-even
  return (unsigned short)(u >> 16);
}

__device__ __forceinline__ void gld16(const void* g, void* l) {
  __builtin_amdgcn_global_load_lds(
      (const __attribute__((address_space(1))) unsigned int*)g,
      (__attribute__((address_space(3))) unsigned int*)l, 16, 0, 0);
}

// ---------------------------------------------------------------------------
// Router: scores = sigmoid(x @ gw^T); top-8; renorm; *2.5.
// Emits per-expert (weight,token) pair lists + counts (atomic append).
// ---------------------------------------------------------------------------
__global__ __launch_bounds__(256) void router_kernel(
    const float* __restrict__ x, const float* __restrict__ gw,
    int* __restrict__ cnt, unsigned int* __restrict__ pairs)
{
  const int t = blockIdx.x;
  __shared__ float xs[H_DIM];
  __shared__ float sc[E_NUM];
  const float4* xr = (const float4*)(x + (long)t * H_DIM);
  for (int i = threadIdx.x; i < H_DIM / 4; i += 256) ((float4*)xs)[i] = xr[i];
  __syncthreads();
  const int e = threadIdx.x >> 3, p = threadIdx.x & 7;
  const float4* ga = (const float4*)(gw + (long)e * H_DIM);
  const float4* xa = (const float4*)xs;
  float s = 0.f;
  #pragma unroll 4
  for (int i = p * 64; i < p * 64 + 64; ++i) {
    float4 a = ga[i], b = xa[i];
    s += a.x * b.x + a.y * b.y + a.z * b.z + a.w * b.w;
  }
  s += __shfl_down(s, 4, 8);
  s += __shfl_down(s, 2, 8);
  s += __shfl_down(s, 1, 8);
  if (p == 0) sc[e] = 1.f / (1.f + expf(-s));
  __syncthreads();
  if (threadIdx.x == 0) {
    float v[E_NUM];
    #pragma unroll
    for (int i = 0; i < E_NUM; ++i) v[i] = sc[i];
    unsigned mask = 0; float sum = 0.f;
    int sel[8]; float wv[8];
    for (int k = 0; k < 8; ++k) {
      float best = -1.f; int bi = 0;
      for (int i = 0; i < E_NUM; ++i)
        if (!((mask >> i) & 1u) && v[i] > best) { best = v[i]; bi = i; }
      mask |= 1u << bi; sel[k] = bi; wv[k] = best; sum += best;
    }
    const float scale = 2.5f / (sum + 1e-20f);
    for (int k = 0; k < 8; ++k) {
      const int slot = atomicAdd(&cnt[sel[k]], 1);
      if (slot < SLOT_CAP) {
        const unsigned int w16 = (unsigned int)f2bf(wv[k] * scale);
        pairs[sel[k] * SLOT_CAP + slot] = (w16 << 16) | (unsigned int)t;
      }
    }
  }
}

// ---------------------------------------------------------------------------
// Build compact live-tile list: tiles[] = (e<<16)|m0 for m0 < cnt[e] step 128.
// ---------------------------------------------------------------------------
__global__ void build_tiles_kernel(const int* __restrict__ cnt,
                                   unsigned int* __restrict__ tiles,
                                   int* __restrict__ ntp)
{
  if (threadIdx.x == 0 && blockIdx.x == 0) {
    int n = 0;
    for (int e = 0; e < E_NUM; ++e) {
      const int c = cnt[e];
      for (int m0 = 0; m0 < c; m0 += 128)
        tiles[n++] = ((unsigned int)e << 16) | (unsigned int)m0;
    }
    *ntp = n;
  }
}

// ---------------------------------------------------------------------------
// fp32 -> bf16 elementwise (x -> xb)
// ---------------------------------------------------------------------------
__global__ __launch_bounds__(256) void cvt_bf16_kernel(
    const float* __restrict__ in, unsigned short* __restrict__ out, int n4)
{
  int i = blockIdx.x * 256 + threadIdx.x;
  if (i >= n4) return;
  float4 v = ((const float4*)in)[i];
  ushort4 o;
  o.x = f2bf(v.x); o.y = f2bf(v.y); o.z = f2bf(v.z); o.w = f2bf(v.w);
  ((ushort4*)out)[i] = o;
}

// ---------------------------------------------------------------------------
// Transpose + fp32->bf16: in fp32 [R][C] (row-major, ldin=C) -> out bf16 [C][R]
// with out row stride ldout; batched over blockIdx.z.
// ---------------------------------------------------------------------------
__global__ __launch_bounds__(256) void transpose_cvt(
    const float* __restrict__ in, unsigned short* __restrict__ out,
    int R, int C, int ldout, long in_bs, long out_bs)
{
  in  += (long)blockIdx.z * in_bs;
  out += (long)blockIdx.z * out_bs;
  __shared__ float tile[64][65];
  const int c0 = blockIdx.x * 64;
  const int r0 = blockIdx.y * 64;
  const int t = threadIdx.x;
  const int lr = t >> 4;
  const int lc = (t & 15) << 2;
  #pragma unroll
  for (int rr = 0; rr < 64; rr += 16) {
    float4 v = *(const float4*)(in + (long)(r0 + lr + rr) * C + c0 + lc);
    tile[lr + rr][lc + 0] = v.x;
    tile[lr + rr][lc + 1] = v.y;
    tile[lr + rr][lc + 2] = v.z;
    tile[lr + rr][lc + 3] = v.w;
  }
  __syncthreads();
  #pragma unroll
  for (int rr = 0; rr < 64; rr += 16) {
    const int c = c0 + lr + rr;
    ushort4 o;
    o.x = f2bf(tile[lc + 0][lr + rr]);
    o.y = f2bf(tile[lc + 1][lr + rr]);
    o.z = f2bf(tile[lc + 2][lr + rr]);
    o.w = f2bf(tile[lc + 3][lr + rr]);
    *(ushort4*)(out + (long)c * ldout + r0 + lc) = o;
  }
}

// ---------------------------------------------------------------------------
// Sparse gate+up GEMM over compact live-tile list, 2-phase pipelined
// (double-buffered LDS, STAGE(next) before COMPUTE(cur), 1 barrier/iter).
// A rows gathered from xb via per-expert token list; writes compact
// act[e][slot][I]. XOR-swizzled LDS (linear gld16 dest, pre-swizzled source,
// XOR on ds_read). Block: 256 thr (4 waves 2x2), tile 128(slots) x 64(I).
// ---------------------------------------------------------------------------
__global__ __launch_bounds__(256) void gate_up_moe_kernel(
    const unsigned short* __restrict__ xb,
    const unsigned short* __restrict__ bgT,
    const unsigned short* __restrict__ buT,
    const int* __restrict__ cnt,
    const unsigned int* __restrict__ pairs,
    const unsigned int* __restrict__ tiles,
    const int* __restrict__ ntp,
    unsigned short* __restrict__ act)
{
  const int ti = blockIdx.x;
  if (ti >= *ntp) return;
  const unsigned int tile = tiles[ti];
  const int e  = (int)(tile >> 16);
  const int m0 = (int)(tile & 0xFFFFu);
  const int cnte = cnt[e];
  const int n0 = blockIdx.y * 64;
  const unsigned short* Bg = bgT + ((long)e * I_DIM + n0) * H_DIM;
  const unsigned short* Bu = buT + ((long)e * I_DIM + n0) * H_DIM;

  __shared__ unsigned short sA[2][128 * 64];
  __shared__ unsigned short sBg[2][64 * 64];
  __shared__ unsigned short sBu[2][64 * 64];

  const int tid = threadIdx.x;
  const int lane = tid & 63;
  const int wid = tid >> 6;
  const int wm = wid >> 1, wn = wid & 1;
  const int l15 = lane & 15;
  const int lk  = (lane >> 4) * 8;
  const int srow = tid >> 3;
  const int scol = (tid & 7) * 8;
  const int scolsw = (((tid & 7) ^ ((tid >> 3) & 7))) * 8;
  const int ksw = (l15 & 7) << 3;

  const unsigned short* asrc[4];
  #pragma unroll
  for (int r = 0; r < 4; ++r) {
    const int slot = m0 + r * 32 + srow;
    const unsigned int pr = (slot < cnte) ? pairs[e * SLOT_CAP + slot] : 0u;
    asrc[r] = xb + (long)(pr & 0xFFFFu) * H_DIM + scolsw;
  }

  const f32x4 fz = {0.f, 0.f, 0.f, 0.f};
  f32x4 accg[4][2], accu[4][2];
  #pragma unroll
  for (int i = 0; i < 4; ++i)
    #pragma unroll
    for (int j = 0; j < 2; ++j) { accg[i][j] = fz; accu[i][j] = fz; }

#define STAGE_GU(buf, k0) do {                                                 \
    _Pragma("unroll")                                                          \
    for (int r = 0; r < 4; ++r)                                                \
      gld16(asrc[r] + (k0), sA[buf] + (r * 32 + srow) * 64 + scol);            \
    _Pragma("unroll")                                                          \
    for (int r = 0; r < 2; ++r) {                                              \
      gld16(Bg + (long)(r * 32 + srow) * H_DIM + (k0) + scolsw,                \
            sBg[buf] + (r * 32 + srow) * 64 + scol);                           \
      gld16(Bu + (long)(r * 32 + srow) * H_DIM + (k0) + scolsw,                \
            sBu[buf] + (r * 32 + srow) * 64 + scol);                           \
    }                                                                          \
  } while (0)

#define COMP_GU(buf) do {                                                      \
    _Pragma("unroll")                                                          \
    for (int kk = 0; kk < 2; ++kk) {                                           \
      const int ko = kk * 32 + lk;                                             \
      bf16x8 a[4], g[2], u[2];                                                 \
      _Pragma("unroll")                                                        \
      for (int mi = 0; mi < 4; ++mi)                                           \
        a[mi] = *(const bf16x8*)(sA[buf] + (wm * 64 + mi * 16 + l15) * 64 +    \
                                 (ko ^ ksw));                                  \
      _Pragma("unroll")                                                        \
      for (int ni = 0; ni < 2; ++ni) {                                         \
        g[ni] = *(const bf16x8*)(sBg[buf] + (wn * 32 + ni * 16 + l15) * 64 +   \
                                 (ko ^ ksw));                                  \
        u[ni] = *(const bf16x8*)(sBu[buf] + (wn * 32 + ni * 16 + l15) * 64 +   \
                                 (ko ^ ksw));                                  \
      }                                                                        \
      _Pragma("unroll")                                                        \
      for (int mi = 0; mi < 4; ++mi)                                           \
        _Pragma("unroll")                                                      \
        for (int ni = 0; ni < 2; ++ni) {                                       \
          accg[mi][ni] = __builtin_amdgcn_mfma_f32_16x16x32_bf16(              \
              a[mi], g[ni], accg[mi][ni], 0, 0, 0);                            \
          accu[mi][ni] = __builtin_amdgcn_mfma_f32_16x16x32_bf16(              \
              a[mi], u[ni], accu[mi][ni], 0, 0, 0);                            \
        }                                                                      \
    }                                                                          \
  } while (0)

  STAGE_GU(0, 0);
  __syncthreads();
  // NT = H_DIM/64 = 32 (even) -> unrolled-by-2 ping-pong, 1 barrier/iter
  for (int t = 0; t < 32; t += 2) {
    if (t + 1 < 32) STAGE_GU(1, (t + 1) * 64);
    COMP_GU(0);
    __syncthreads();
    if (t + 2 < 32) STAGE_GU(0, (t + 2) * 64);
    COMP_GU(1);
    __syncthreads();
  }
#undef STAGE_GU
#undef COMP_GU

  const int colb = n0 + wn * 32;
  #pragma unroll
  for (int mi = 0; mi < 4; ++mi) {
    #pragma unroll
    for (int r = 0; r < 4; ++r) {
      const int slot = m0 + wm * 64 + mi * 16 + (lane >> 4) * 4 + r;
      if (slot < cnte) {
        const unsigned int pr = pairs[e * SLOT_CAP + slot];
        const float w = __uint_as_float(pr & 0xFFFF0000u);
        #pragma unroll
        for (int ni = 0; ni < 2; ++ni) {
          const float gv = accg[mi][ni][r];
          const float uv = accu[mi][ni][r];
          const float sv = (gv / (1.f + expf(-gv))) * uv * w;
          act[((long)e * SLOT_CAP + slot) * I_DIM + colb + ni * 16 + l15] =
              f2bf(sv);
        }
      }
    }
  }
}

// ---------------------------------------------------------------------------
// Dense gate+up GEMM for the shared expert (weight 1) -> hs[T][IS].
// (unpipelined m97 core, small: ~34 GF)
// ---------------------------------------------------------------------------
__global__ __launch_bounds__(256) void gate_up_shared_kernel(
    const unsigned short* __restrict__ xb,
    const unsigned short* __restrict__ bgT,
    const unsigned short* __restrict__ buT,
    unsigned short* __restrict__ hs)
{
  const int t0 = blockIdx.x * 128;
  const int n0 = blockIdx.y * 64;
  const unsigned short* Bg = bgT + (long)n0 * H_DIM;
  const unsigned short* Bu = buT + (long)n0 * H_DIM;
  const unsigned short* A  = xb + (long)t0 * H_DIM;

  __shared__ unsigned short sA[128 * 64];
  __shared__ unsigned short sBg[64 * 64];
  __shared__ unsigned short sBu[64 * 64];

  const int tid = threadIdx.x;
  const int lane = tid & 63;
  const int wid = tid >> 6;
  const int wm = wid >> 1, wn = wid & 1;
  const int l15 = lane & 15;
  const int lk  = (lane >> 4) * 8;
  const int srow = tid >> 3;
  const int scol = (tid & 7) * 8;
  const int scolsw = (((tid & 7) ^ ((tid >> 3) & 7))) * 8;
  const int ksw = (l15 & 7) << 3;

  const f32x4 fz = {0.f, 0.f, 0.f, 0.f};
  f32x4 accg[4][2], accu[4][2];
  #pragma unroll
  for (int i = 0; i < 4; ++i)
    #pragma unroll
    for (int j = 0; j < 2; ++j) { accg[i][j] = fz; accu[i][j] = fz; }

  for (int k0 = 0; k0 < H_DIM; k0 += 64) {
    #pragma unroll
    for (int r = 0; r < 4; ++r)
      gld16(A + (long)(r * 32 + srow) * H_DIM + k0 + scolsw,
            sA + (r * 32 + srow) * 64 + scol);
    #pragma unroll
    for (int r = 0; r < 2; ++r) {
      gld16(Bg + (long)(r * 32 + srow) * H_DIM + k0 + scolsw,
            sBg + (r * 32 + srow) * 64 + scol);
      gld16(Bu + (long)(r * 32 + srow) * H_DIM + k0 + scolsw,
            sBu + (r * 32 + srow) * 64 + scol);
    }
    __syncthreads();
    #pragma unroll
    for (int kk = 0; kk < 2; ++kk) {
      const int ko = kk * 32 + lk;
      bf16x8 a[4], g[2], u[2];
      #pragma unroll
      for (int mi = 0; mi < 4; ++mi)
        a[mi] = *(const bf16x8*)(sA + (wm * 64 + mi * 16 + l15) * 64 + (ko ^ ksw));
      #pragma unroll
      for (int ni = 0; ni < 2; ++ni) {
        g[ni] = *(const bf16x8*)(sBg + (wn * 32 + ni * 16 + l15) * 64 + (ko ^ ksw));
        u[ni] = *(const bf16x8*)(sBu + (wn * 32 + ni * 16 + l15) * 64 + (ko ^ ksw));
      }
      #pragma unroll
      for (int mi = 0; mi < 4; ++mi)
        #pragma unroll
        for (int ni = 0; ni < 2; ++ni) {
          accg[mi][ni] = __builtin_amdgcn_mfma_f32_16x16x32_bf16(a[mi], g[ni], accg[mi][ni], 0, 0, 0);
          accu[mi][ni] = __builtin_amdgcn_mfma_f32_16x16x32_bf16(a[mi], u[ni], accu[mi][ni], 0, 0, 0);
        }
    }
    __syncthreads();
  }

  const int colb = n0 + wn * 32;
  #pragma unroll
  for (int mi = 0; mi < 4; ++mi) {
    #pragma unroll
    for (int r = 0; r < 4; ++r) {
      const int t = t0 + wm * 64 + mi * 16 + (lane >> 4) * 4 + r;
      #pragma unroll
      for (int ni = 0; ni < 2; ++ni) {
        const float gv = accg[mi][ni][r];
        const float uv = accu[mi][ni][r];
        hs[(long)t * IS_DIM + colb + ni * 16 + l15] =
            f2bf((gv / (1.f + expf(-gv))) * uv);
      }
    }
  }
}

// ---------------------------------------------------------------------------
// Shared-expert down GEMM: out[T,H] = hs[T,IS] @ wsdT^T (plain fp32 stores;
// runs BEFORE down_moe's atomic adds).
// ---------------------------------------------------------------------------
__global__ __launch_bounds__(256) void down_shared_kernel(
    const unsigned short* __restrict__ hs,
    const unsigned short* __restrict__ wdT,   // pass wdT + 32768 col base
    float* __restrict__ out)
{
  const int t0 = blockIdx.x * 128;
  const int n0 = blockIdx.y * 64;
  const unsigned short* A = hs + (long)t0 * IS_DIM;
  const unsigned short* B = wdT + (long)n0 * K_TOT;

  __shared__ unsigned short sA[128 * 64];
  __shared__ unsigned short sB[64 * 64];

  const int tid = threadIdx.x;
  const int lane = tid & 63;
  const int wid = tid >> 6;
  const int wm = wid >> 1, wn = wid & 1;
  const int l15 = lane & 15;
  const int lk  = (lane >> 4) * 8;
  const int srow = tid >> 3;
  const int scol = (tid & 7) * 8;
  const int scolsw = (((tid & 7) ^ ((tid >> 3) & 7))) * 8;
  const int ksw = (l15 & 7) << 3;

  const f32x4 fz = {0.f, 0.f, 0.f, 0.f};
  f32x4 acc[4][2];
  #pragma unroll
  for (int i = 0; i < 4; ++i)
    #pragma unroll
    for (int j = 0; j < 2; ++j) acc[i][j] = fz;

  for (int k0 = 0; k0 < IS_DIM; k0 += 64) {
    #pragma unroll
    for (int r = 0; r < 4; ++r)
      gld16(A + (long)(r * 32 + srow) * IS_DIM + k0 + scolsw,
            sA + (r * 32 + srow) * 64 + scol);
    #pragma unroll
    for (int r = 0; r < 2; ++r)
      gld16(B + (long)(r * 32 + srow) * K_TOT + k0 + scolsw,
            sB + (r * 32 + srow) * 64 + scol);
    __syncthreads();
    #pragma unroll
    for (int kk = 0; kk < 2; ++kk) {
      const int ko = kk * 32 + lk;
      bf16x8 a[4], b[2];
      #pragma unroll
      for (int mi = 0; mi < 4; ++mi)
        a[mi] = *(const bf16x8*)(sA + (wm * 64 + mi * 16 + l15) * 64 + (ko ^ ksw));
      #pragma unroll
      for (int ni = 0; ni < 2; ++ni)
        b[ni] = *(const bf16x8*)(sB + (wn * 32 + ni * 16 + l15) * 64 + (ko ^ ksw));
      #pragma unroll
      for (int mi = 0; mi < 4; ++mi)
        #pragma unroll
        for (int ni = 0; ni < 2; ++ni)
          acc[mi][ni] = __builtin_amdgcn_mfma_f32_16x16x32_bf16(a[mi], b[ni], acc[mi][ni], 0, 0, 0);
    }
    __syncthreads();
  }

  #pragma unroll
  for (int mi = 0; mi < 4; ++mi) {
    #pragma unroll
    for (int r = 0; r < 4; ++r) {
      const int t = t0 + wm * 64 + mi * 16 + (lane >> 4) * 4 + r;
      #pragma unroll
      for (int ni = 0; ni < 2; ++ni)
        out[(long)t * H_DIM + n0 + wn * 32 + ni * 16 + l15] = acc[mi][ni][r];
    }
  }
}

// ---------------------------------------------------------------------------
// Sparse expert-down GEMM over live tiles, 2-phase pipelined:
// C[slot, hcol] = act[e][slot][:] @ wd_e  ; atomicAdd-scatter to out[tok].
// B = wdT rows [hcol][e*I .. e*I+I) (row stride K_TOT). K = I_DIM = 1024.
// ---------------------------------------------------------------------------
__global__ __launch_bounds__(256) void down_moe_kernel(
    const unsigned short* __restrict__ act,
    const unsigned short* __restrict__ wdT,
    const int* __restrict__ cnt,
    const unsigned int* __restrict__ pairs,
    const unsigned int* __restrict__ tiles,
    const int* __restrict__ ntp,
    float* __restrict__ out)
{
  const int ti = blockIdx.x;
  if (ti >= *ntp) return;
  const unsigned int tile = tiles[ti];
  const int e  = (int)(tile >> 16);
  const int m0 = (int)(tile & 0xFFFFu);
  const int cnte = cnt[e];
  const int n0 = blockIdx.y * 64;
  const unsigned short* A = act + ((long)e * SLOT_CAP + m0) * I_DIM;
  const unsigned short* B = wdT + (long)n0 * K_TOT + (long)e * I_DIM;

  __shared__ unsigned short sA[2][128 * 64];
  __shared__ unsigned short sB[2][64 * 64];

  const int tid = threadIdx.x;
  const int lane = tid & 63;
  const int wid = tid >> 6;
  const int wm = wid >> 1, wn = wid & 1;
  const int l15 = lane & 15;
  const int lk  = (lane >> 4) * 8;
  const int srow = tid >> 3;
  const int scol = (tid & 7) * 8;
  const int scolsw = (((tid & 7) ^ ((tid >> 3) & 7))) * 8;
  const int ksw = (l15 & 7) << 3;

  const f32x4 fz = {0.f, 0.f, 0.f, 0.f};
  f32x4 acc[4][2];
  #pragma unroll
  for (int i = 0; i < 4; ++i)
    #pragma unroll
    for (int j = 0; j < 2; ++j) acc[i][j] = fz;

#define STAGE_DN(buf, k0) do {                                                 \
    _Pragma("unroll")                                                          \
    for (int r = 0; r < 4; ++r)                                                \
      gld16(A + (long)(r * 32 + srow) * I_DIM + (k0) + scolsw,                 \
            sA[buf] + (r * 32 + srow) * 64 + scol);                            \
    _Pragma("unroll")                                                          \
    for (int r = 0; r < 2; ++r)                                                \
      gld16(B + (long)(r * 32 + srow) * K_TOT + (k0) + scolsw,                 \
            sB[buf] + (r * 32 + srow) * 64 + scol);                            \
  } while (0)

#define COMP_DN(buf) do {                                                      \
    _Pragma("unroll")                                                          \
    for (int kk = 0; kk < 2; ++kk) {                                           \
      const int ko = kk * 32 + lk;                                             \
      bf16x8 a[4], b[2];                                                       \
      _Pragma("unroll")                                                        \
      for (int mi = 0; mi < 4; ++mi)                                           \
        a[mi] = *(const bf16x8*)(sA[buf] + (wm * 64 + mi * 16 + l15) * 64 +    \
                                 (ko ^ ksw));                                  \
      _Pragma("unroll")                                                        \
      for (int ni = 0; ni < 2; ++ni)                                           \
        b[ni] = *(const bf16x8*)(sB[buf] + (wn * 32 + ni * 16 + l15) * 64 +    \
                                 (ko ^ ksw));                                  \
      _Pragma("unroll")                                                        \
      for (int mi = 0; mi < 4; ++mi)                                           \
        _Pragma("unroll")                                                      \
        for (int ni = 0; ni < 2; ++ni)                                         \
          acc[mi][ni] = __builtin_amdgcn_mfma_f32_16x16x32_bf16(               \
              a[mi], b[ni], acc[mi][ni], 0, 0, 0);                             \
    }                                                                          \
  } while (0)

  STAGE_DN(0, 0);
  __syncthreads();
  // NT = I_DIM/64 = 16 (even)
  for (int t = 0; t < 16; t += 2) {
    if (t + 1 < 16) STAGE_DN(1, (t + 1) * 64);
    COMP_DN(0);
    __syncthreads();
    if (t + 2 < 16) STAGE_DN(0, (t + 2) * 64);
    COMP_DN(1);
    __syncthreads();
  }
#undef STAGE_DN
#undef COMP_DN

  #pragma unroll
  for (int mi = 0; mi < 4; ++mi) {
    #pragma unroll
    for (int r = 0; r < 4; ++r) {
      const int slot = m0 + wm * 64 + mi * 16 + (lane >> 4) * 4 + r;
      if (slot < cnte) {
        const int tok = (int)(pairs[e * SLOT_CAP + slot] & 0xFFFFu);
        #pragma unroll
        for (int ni = 0; ni < 2; ++ni)
          atomicAdd(out + (long)tok * H_DIM + n0 + wn * 32 + ni * 16 + l15,
                    acc[mi][ni][r]);
      }
    }
  }
}

// ---------------------------------------------------------------------------
extern "C" void kernel_launch(void* const* d_in, const int* in_sizes, int n_in,
                              void* d_out, int out_size, void* d_ws, size_t ws_size,
                              hipStream_t stream) {
  (void)in_sizes; (void)n_in; (void)out_size; (void)ws_size;
  const float* x   = (const float*)d_in[0];
  const float* gw  = (const float*)d_in[1];
  const float* wg  = (const float*)d_in[2];
  const float* wu  = (const float*)d_in[3];
  const float* wd  = (const float*)d_in[4];
  const float* wsg = (const float*)d_in[5];
  const float* wsu = (const float*)d_in[6];
  const float* wsd = (const float*)d_in[7];
  float* out = (float*)d_out;
  char* ws = (char*)d_ws;

  int*            cnt   = (int*)(ws + OFF_CNT);
  int*            ntp   = (int*)(ws + OFF_NT);
  unsigned int*   tiles = (unsigned int*)(ws + OFF_TILES);
  unsigned int*   pairs = (unsigned int*)(ws + OFF_PAIRS);
  unsigned short* xb    = (unsigned short*)(ws + OFF_XB);
  unsigned short* wgT   = (unsigned short*)(ws + OFF_WGT);
  unsigned short* wuT   = (unsigned short*)(ws + OFF_WUT);
  unsigned short* hsb   = (unsigned short*)(ws + OFF_HS);   // aliases wuT
  unsigned short* wsgT  = (unsigned short*)(ws + OFF_WSGT);
  unsigned short* wsuT  = (unsigned short*)(ws + OFF_WSUT);
  unsigned short* wdT   = (unsigned short*)(ws + OFF_WDT);
  unsigned short* actb  = (unsigned short*)(ws + OFF_ACT);

  hipMemsetAsync(ws + OFF_CNT, 0, 128, stream);

  // router (per-expert token/weight lists), live-tile list, act convert
  router_kernel<<<T_TOK, 256, 0, stream>>>(x, gw, cnt, pairs);
  build_tiles_kernel<<<1, 64, 0, stream>>>(cnt, tiles, ntp);
  cvt_bf16_kernel<<<(T_TOK * H_DIM / 4 + 255) / 256, 256, 0, stream>>>(
      x, xb, T_TOK * H_DIM / 4);

  // weight transpose + bf16 convert
  transpose_cvt<<<dim3(16, 32, 32), 256, 0, stream>>>(
      wg, wgT, H_DIM, I_DIM, H_DIM, (long)H_DIM * I_DIM, (long)I_DIM * H_DIM);
  transpose_cvt<<<dim3(16, 32, 32), 256, 0, stream>>>(
      wu, wuT, H_DIM, I_DIM, H_DIM, (long)H_DIM * I_DIM, (long)I_DIM * H_DIM);
  transpose_cvt<<<dim3(32, 16, 32), 256, 0, stream>>>(
      wd, wdT, I_DIM, H_DIM, K_TOT, (long)I_DIM * H_DIM, (long)I_DIM);
  transpose_cvt<<<dim3(32, 32, 1), 256, 0, stream>>>(
      wsg, wsgT, H_DIM, IS_DIM, H_DIM, 0, 0);
  transpose_cvt<<<dim3(32, 32, 1), 256, 0, stream>>>(
      wsu, wsuT, H_DIM, IS_DIM, H_DIM, 0, 0);
  transpose_cvt<<<dim3(32, 32, 1), 256, 0, stream>>>(
      wsd, wdT + E_NUM * I_DIM, IS_DIM, H_DIM, K_TOT, 0, 0);

  // sparse top-8 gathered experts gate+up -> compact act (weights folded in)
  gate_up_moe_kernel<<<dim3(MAX_TILES, 16), 256, 0, stream>>>(
      xb, wgT, wuT, cnt, pairs, tiles, ntp, actb);

  // shared expert gate+up -> hs (aliases wuT; wuT dead after gate_up_moe)
  gate_up_shared_kernel<<<dim3(16, 32), 256, 0, stream>>>(
      xb, wsgT, wsuT, hsb);

  // shared-expert down writes out (plain stores), then expert down atomic-adds
  down_shared_kernel<<<dim3(16, 32), 256, 0, stream>>>(
      hsb, wdT + E_NUM * I_DIM, out);
  down_moe_kernel<<<dim3(MAX_TILES, 32), 256, 0, stream>>>(
      actb, wdT, cnt, pairs, tiles, ntp, out);
}

// Round 5
// 865.828 us; speedup vs baseline: 1.8280x; 1.1203x over previous
//
#include <hip/hip_runtime.h>

// Problem dims (fixed by the reference)
#define T_TOK 2048      // B*S tokens
#define H_DIM 2048
#define E_NUM 32
#define I_DIM 1024
#define IS_DIM 2048
#define K_TOT (E_NUM * I_DIM + IS_DIM)   // 34816
#define SLOT_CAP 2048   // per-expert token-slot capacity
#define MAX_TILES 160   // sum ceil(cnt_e/128) <= 16384/128 + 32

typedef __bf16 bf16x8 __attribute__((ext_vector_type(8)));
typedef float  f32x4  __attribute__((ext_vector_type(4)));
static_assert(sizeof(bf16x8) == 16, "bf16x8 must be 16B");

// Workspace layout (bytes). Total = 570,688,512.
#define OFF_CNT   ((size_t)0)            // cnt[32] int
#define OFF_NT    ((size_t)128)          // ntiles int
#define OFF_TILES ((size_t)256)          // tiles[160] uint (e<<16|m0)
#define OFF_PAIRS ((size_t)1024)         // pairs[32][2048] uint
#define OFF_XB    ((size_t)263168)       // xb [T,H] bf16
#define OFF_WGT   ((size_t)8651776)      // wgT [E][I][H] bf16
#define OFF_WUT   ((size_t)142869504)    // wuT [E][I][H] bf16 (hs aliases)
#define OFF_HS    OFF_WUT
#define OFF_WSGT  ((size_t)277087232)    // wsgT [IS][H] bf16
#define OFF_WSUT  ((size_t)285475840)    // wsuT [IS][H] bf16
#define OFF_WDT   ((size_t)293864448)    // wdT [H][K_TOT] bf16
#define OFF_ACT   ((size_t)436470784)    // act [32][2048][1024] bf16

__device__ __forceinline__ unsigned short f2bf(float f) {
  unsigned int u = __float_as_uint(f);
  u += 0x7fffu + ((u >> 16) & 1u);   // round-to-nearest-even
  return (unsigned short)(u >> 16);
}

__device__ __forceinline__ void gld16(const void* g, void* l) {
  __builtin_amdgcn_global_load_lds(
      (const __attribute__((address_space(1))) unsigned int*)g,
      (__attribute__((address_space(3))) unsigned int*)l, 16, 0, 0);
}

// ---------------------------------------------------------------------------
// Router: scores = sigmoid(x @ gw^T); top-8; renorm; *2.5 -> pair lists.
// ---------------------------------------------------------------------------
__global__ __launch_bounds__(256) void router_kernel(
    const float* __restrict__ x, const float* __restrict__ gw,
    int* __restrict__ cnt, unsigned int* __restrict__ pairs)
{
  const int t = blockIdx.x;
  __shared__ float xs[H_DIM];
  __shared__ float sc[E_NUM];
  const float4* xr = (const float4*)(x + (long)t * H_DIM);
  for (int i = threadIdx.x; i < H_DIM / 4; i += 256) ((float4*)xs)[i] = xr[i];
  __syncthreads();
  const int e = threadIdx.x >> 3, p = threadIdx.x & 7;
  const float4* ga = (const float4*)(gw + (long)e * H_DIM);
  const float4* xa = (const float4*)xs;
  float s = 0.f;
  #pragma unroll 4
  for (int i = p * 64; i < p * 64 + 64; ++i) {
    float4 a = ga[i], b = xa[i];
    s += a.x * b.x + a.y * b.y + a.z * b.z + a.w * b.w;
  }
  s += __shfl_down(s, 4, 8);
  s += __shfl_down(s, 2, 8);
  s += __shfl_down(s, 1, 8);
  if (p == 0) sc[e] = 1.f / (1.f + expf(-s));
  __syncthreads();
  if (threadIdx.x == 0) {
    float v[E_NUM];
    #pragma unroll
    for (int i = 0; i < E_NUM; ++i) v[i] = sc[i];
    unsigned mask = 0; float sum = 0.f;
    int sel[8]; float wv[8];
    for (int k = 0; k < 8; ++k) {
      float best = -1.f; int bi = 0;
      for (int i = 0; i < E_NUM; ++i)
        if (!((mask >> i) & 1u) && v[i] > best) { best = v[i]; bi = i; }
      mask |= 1u << bi; sel[k] = bi; wv[k] = best; sum += best;
    }
    const float scale = 2.5f / (sum + 1e-20f);
    for (int k = 0; k < 8; ++k) {
      const int slot = atomicAdd(&cnt[sel[k]], 1);
      if (slot < SLOT_CAP) {
        const unsigned int w16 = (unsigned int)f2bf(wv[k] * scale);
        pairs[sel[k] * SLOT_CAP + slot] = (w16 << 16) | (unsigned int)t;
      }
    }
  }
}

// ---------------------------------------------------------------------------
__global__ void build_tiles_kernel(const int* __restrict__ cnt,
                                   unsigned int* __restrict__ tiles,
                                   int* __restrict__ ntp)
{
  if (threadIdx.x == 0 && blockIdx.x == 0) {
    int n = 0;
    for (int e = 0; e < E_NUM; ++e) {
      const int c = cnt[e];
      for (int m0 = 0; m0 < c; m0 += 128)
        tiles[n++] = ((unsigned int)e << 16) | (unsigned int)m0;
    }
    *ntp = n;
  }
}

// ---------------------------------------------------------------------------
__global__ __launch_bounds__(256) void cvt_bf16_kernel(
    const float* __restrict__ in, unsigned short* __restrict__ out, int n4)
{
  int i = blockIdx.x * 256 + threadIdx.x;
  if (i >= n4) return;
  float4 v = ((const float4*)in)[i];
  ushort4 o;
  o.x = f2bf(v.x); o.y = f2bf(v.y); o.z = f2bf(v.z); o.w = f2bf(v.w);
  ((ushort4*)out)[i] = o;
}

// ---------------------------------------------------------------------------
// Fused transpose+cvt over 6 weight tensors (descriptor table, 1D grid).
// Per block: 64x64 tile, in fp32 [R][C] -> out bf16 [C][R] (row stride ldout).
// ---------------------------------------------------------------------------
struct TDescTable {
  const float* in[6];
  unsigned short* out[6];
  int C[6];
  int ldout[6];
  long in_bs[6];
  long out_bs[6];
  int nbx[6];
  int nbxy[6];
  int start[7];
};

__global__ __launch_bounds__(256) void transpose_fused(TDescTable td)
{
  const int bid = blockIdx.x;
  int i = 0;
  while (i < 5 && bid >= td.start[i + 1]) ++i;
  const int local = bid - td.start[i];
  const int bz = local / td.nbxy[i];
  const int rem = local % td.nbxy[i];
  const int by = rem / td.nbx[i];
  const int bx = rem % td.nbx[i];
  const float* in = td.in[i] + (long)bz * td.in_bs[i];
  unsigned short* out = td.out[i] + (long)bz * td.out_bs[i];
  const int C = td.C[i], ldout = td.ldout[i];

  __shared__ float tile[64][65];
  const int c0 = bx * 64;
  const int r0 = by * 64;
  const int t = threadIdx.x;
  const int lr = t >> 4;
  const int lc = (t & 15) << 2;
  #pragma unroll
  for (int rr = 0; rr < 64; rr += 16) {
    float4 v = *(const float4*)(in + (long)(r0 + lr + rr) * C + c0 + lc);
    tile[lr + rr][lc + 0] = v.x;
    tile[lr + rr][lc + 1] = v.y;
    tile[lr + rr][lc + 2] = v.z;
    tile[lr + rr][lc + 3] = v.w;
  }
  __syncthreads();
  #pragma unroll
  for (int rr = 0; rr < 64; rr += 16) {
    const int c = c0 + lr + rr;
    ushort4 o;
    o.x = f2bf(tile[lc + 0][lr + rr]);
    o.y = f2bf(tile[lc + 1][lr + rr]);
    o.z = f2bf(tile[lc + 2][lr + rr]);
    o.w = f2bf(tile[lc + 3][lr + rr]);
    *(ushort4*)(out + (long)c * ldout + r0 + lc) = o;
  }
}

// ---------------------------------------------------------------------------
// Sparse gate+up GEMM, 512 threads (8 waves, 4Mx2N), tile 128x64, BK=64,
// 2-phase dbuf pipeline, XOR-swizzled LDS, gathered A rows, grid (n0, tile).
// ---------------------------------------------------------------------------
__global__ __launch_bounds__(512, 4) void gate_up_moe_kernel(
    const unsigned short* __restrict__ xb,
    const unsigned short* __restrict__ bgT,
    const unsigned short* __restrict__ buT,
    const int* __restrict__ cnt,
    const unsigned int* __restrict__ pairs,
    const unsigned int* __restrict__ tiles,
    const int* __restrict__ ntp,
    unsigned short* __restrict__ act)
{
  const int ti = blockIdx.y;
  if (ti >= *ntp) return;
  const unsigned int tile = tiles[ti];
  const int e  = (int)(tile >> 16);
  const int m0 = (int)(tile & 0xFFFFu);
  const int cnte = cnt[e];
  const int n0 = blockIdx.x * 64;
  const unsigned short* Bg = bgT + ((long)e * I_DIM + n0) * H_DIM;
  const unsigned short* Bu = buT + ((long)e * I_DIM + n0) * H_DIM;

  __shared__ unsigned short sA[2][128 * 64];
  __shared__ unsigned short sBg[2][64 * 64];
  __shared__ unsigned short sBu[2][64 * 64];

  const int tid = threadIdx.x;
  const int lane = tid & 63;
  const int wid = tid >> 6;           // 0..7
  const int wm = wid >> 1, wn = wid & 1;
  const int l15 = lane & 15;
  const int lk  = (lane >> 4) * 8;
  const int srow = tid >> 3;          // 0..63
  const int scol = (tid & 7) * 8;
  const int scolsw = (((tid & 7) ^ (srow & 7))) * 8;
  const int ksw = (l15 & 7) << 3;

  const unsigned short* asrc[2];
  #pragma unroll
  for (int r = 0; r < 2; ++r) {
    const int slot = m0 + r * 64 + srow;
    const unsigned int pr = (slot < cnte) ? pairs[e * SLOT_CAP + slot] : 0u;
    asrc[r] = xb + (long)(pr & 0xFFFFu) * H_DIM + scolsw;
  }

  const f32x4 fz = {0.f, 0.f, 0.f, 0.f};
  f32x4 accg[2][2], accu[2][2];
  #pragma unroll
  for (int i = 0; i < 2; ++i)
    #pragma unroll
    for (int j = 0; j < 2; ++j) { accg[i][j] = fz; accu[i][j] = fz; }

#define STAGE_GU(buf, k0) do {                                                 \
    gld16(asrc[0] + (k0), sA[buf] + srow * 64 + scol);                         \
    gld16(asrc[1] + (k0), sA[buf] + (64 + srow) * 64 + scol);                  \
    gld16(Bg + (long)srow * H_DIM + (k0) + scolsw,                             \
          sBg[buf] + srow * 64 + scol);                                        \
    gld16(Bu + (long)srow * H_DIM + (k0) + scolsw,                             \
          sBu[buf] + srow * 64 + scol);                                        \
  } while (0)

#define COMP_GU(buf) do {                                                      \
    _Pragma("unroll")                                                          \
    for (int kk = 0; kk < 2; ++kk) {                                           \
      const int ko = kk * 32 + lk;                                             \
      bf16x8 a[2], g[2], u[2];                                                 \
      _Pragma("unroll")                                                        \
      for (int mi = 0; mi < 2; ++mi)                                           \
        a[mi] = *(const bf16x8*)(sA[buf] + (wm * 32 + mi * 16 + l15) * 64 +    \
                                 (ko ^ ksw));                                  \
      _Pragma("unroll")                                                        \
      for (int ni = 0; ni < 2; ++ni) {                                         \
        g[ni] = *(const bf16x8*)(sBg[buf] + (wn * 32 + ni * 16 + l15) * 64 +   \
                                 (ko ^ ksw));                                  \
        u[ni] = *(const bf16x8*)(sBu[buf] + (wn * 32 + ni * 16 + l15) * 64 +   \
                                 (ko ^ ksw));                                  \
      }                                                                        \
      _Pragma("unroll")                                                        \
      for (int mi = 0; mi < 2; ++mi)                                           \
        _Pragma("unroll")                                                      \
        for (int ni = 0; ni < 2; ++ni) {                                       \
          accg[mi][ni] = __builtin_amdgcn_mfma_f32_16x16x32_bf16(              \
              a[mi], g[ni], accg[mi][ni], 0, 0, 0);                            \
          accu[mi][ni] = __builtin_amdgcn_mfma_f32_16x16x32_bf16(              \
              a[mi], u[ni], accu[mi][ni], 0, 0, 0);                            \
        }                                                                      \
    }                                                                          \
  } while (0)

  STAGE_GU(0, 0);
  __syncthreads();
  for (int t = 0; t < 32; t += 2) {
    if (t + 1 < 32) STAGE_GU(1, (t + 1) * 64);
    COMP_GU(0);
    __syncthreads();
    if (t + 2 < 32) STAGE_GU(0, (t + 2) * 64);
    COMP_GU(1);
    __syncthreads();
  }
#undef STAGE_GU
#undef COMP_GU

  const int colb = n0 + wn * 32;
  #pragma unroll
  for (int mi = 0; mi < 2; ++mi) {
    #pragma unroll
    for (int r = 0; r < 4; ++r) {
      const int slot = m0 + wm * 32 + mi * 16 + (lane >> 4) * 4 + r;
      if (slot < cnte) {
        const unsigned int pr = pairs[e * SLOT_CAP + slot];
        const float w = __uint_as_float(pr & 0xFFFF0000u);
        #pragma unroll
        for (int ni = 0; ni < 2; ++ni) {
          const float gv = accg[mi][ni][r];
          const float uv = accu[mi][ni][r];
          const float sv = (gv / (1.f + expf(-gv))) * uv * w;
          act[((long)e * SLOT_CAP + slot) * I_DIM + colb + ni * 16 + l15] =
              f2bf(sv);
        }
      }
    }
  }
}

// ---------------------------------------------------------------------------
// Dense gate+up GEMM for the shared expert (weight 1) -> hs[T][IS].
// ---------------------------------------------------------------------------
__global__ __launch_bounds__(256) void gate_up_shared_kernel(
    const unsigned short* __restrict__ xb,
    const unsigned short* __restrict__ bgT,
    const unsigned short* __restrict__ buT,
    unsigned short* __restrict__ hs)
{
  const int t0 = blockIdx.x * 128;
  const int n0 = blockIdx.y * 64;
  const unsigned short* Bg = bgT + (long)n0 * H_DIM;
  const unsigned short* Bu = buT + (long)n0 * H_DIM;
  const unsigned short* A  = xb + (long)t0 * H_DIM;

  __shared__ unsigned short sA[128 * 64];
  __shared__ unsigned short sBg[64 * 64];
  __shared__ unsigned short sBu[64 * 64];

  const int tid = threadIdx.x;
  const int lane = tid & 63;
  const int wid = tid >> 6;
  const int wm = wid >> 1, wn = wid & 1;
  const int l15 = lane & 15;
  const int lk  = (lane >> 4) * 8;
  const int srow = tid >> 3;
  const int scol = (tid & 7) * 8;
  const int scolsw = (((tid & 7) ^ ((tid >> 3) & 7))) * 8;
  const int ksw = (l15 & 7) << 3;

  const f32x4 fz = {0.f, 0.f, 0.f, 0.f};
  f32x4 accg[4][2], accu[4][2];
  #pragma unroll
  for (int i = 0; i < 4; ++i)
    #pragma unroll
    for (int j = 0; j < 2; ++j) { accg[i][j] = fz; accu[i][j] = fz; }

  for (int k0 = 0; k0 < H_DIM; k0 += 64) {
    #pragma unroll
    for (int r = 0; r < 4; ++r)
      gld16(A + (long)(r * 32 + srow) * H_DIM + k0 + scolsw,
            sA + (r * 32 + srow) * 64 + scol);
    #pragma unroll
    for (int r = 0; r < 2; ++r) {
      gld16(Bg + (long)(r * 32 + srow) * H_DIM + k0 + scolsw,
            sBg + (r * 32 + srow) * 64 + scol);
      gld16(Bu + (long)(r * 32 + srow) * H_DIM + k0 + scolsw,
            sBu + (r * 32 + srow) * 64 + scol);
    }
    __syncthreads();
    #pragma unroll
    for (int kk = 0; kk < 2; ++kk) {
      const int ko = kk * 32 + lk;
      bf16x8 a[4], g[2], u[2];
      #pragma unroll
      for (int mi = 0; mi < 4; ++mi)
        a[mi] = *(const bf16x8*)(sA + (wm * 64 + mi * 16 + l15) * 64 + (ko ^ ksw));
      #pragma unroll
      for (int ni = 0; ni < 2; ++ni) {
        g[ni] = *(const bf16x8*)(sBg + (wn * 32 + ni * 16 + l15) * 64 + (ko ^ ksw));
        u[ni] = *(const bf16x8*)(sBu + (wn * 32 + ni * 16 + l15) * 64 + (ko ^ ksw));
      }
      #pragma unroll
      for (int mi = 0; mi < 4; ++mi)
        #pragma unroll
        for (int ni = 0; ni < 2; ++ni) {
          accg[mi][ni] = __builtin_amdgcn_mfma_f32_16x16x32_bf16(a[mi], g[ni], accg[mi][ni], 0, 0, 0);
          accu[mi][ni] = __builtin_amdgcn_mfma_f32_16x16x32_bf16(a[mi], u[ni], accu[mi][ni], 0, 0, 0);
        }
    }
    __syncthreads();
  }

  const int colb = n0 + wn * 32;
  #pragma unroll
  for (int mi = 0; mi < 4; ++mi) {
    #pragma unroll
    for (int r = 0; r < 4; ++r) {
      const int t = t0 + wm * 64 + mi * 16 + (lane >> 4) * 4 + r;
      #pragma unroll
      for (int ni = 0; ni < 2; ++ni) {
        const float gv = accg[mi][ni][r];
        const float uv = accu[mi][ni][r];
        hs[(long)t * IS_DIM + colb + ni * 16 + l15] =
            f2bf((gv / (1.f + expf(-gv))) * uv);
      }
    }
  }
}

// ---------------------------------------------------------------------------
// Shared-expert down GEMM: out[T,H] = hs[T,IS] @ wsdT^T (plain fp32 stores).
// ---------------------------------------------------------------------------
__global__ __launch_bounds__(256) void down_shared_kernel(
    const unsigned short* __restrict__ hs,
    const unsigned short* __restrict__ wdT,
    float* __restrict__ out)
{
  const int t0 = blockIdx.x * 128;
  const int n0 = blockIdx.y * 64;
  const unsigned short* A = hs + (long)t0 * IS_DIM;
  const unsigned short* B = wdT + (long)n0 * K_TOT;

  __shared__ unsigned short sA[128 * 64];
  __shared__ unsigned short sB[64 * 64];

  const int tid = threadIdx.x;
  const int lane = tid & 63;
  const int wid = tid >> 6;
  const int wm = wid >> 1, wn = wid & 1;
  const int l15 = lane & 15;
  const int lk  = (lane >> 4) * 8;
  const int srow = tid >> 3;
  const int scol = (tid & 7) * 8;
  const int scolsw = (((tid & 7) ^ ((tid >> 3) & 7))) * 8;
  const int ksw = (l15 & 7) << 3;

  const f32x4 fz = {0.f, 0.f, 0.f, 0.f};
  f32x4 acc[4][2];
  #pragma unroll
  for (int i = 0; i < 4; ++i)
    #pragma unroll
    for (int j = 0; j < 2; ++j) acc[i][j] = fz;

  for (int k0 = 0; k0 < IS_DIM; k0 += 64) {
    #pragma unroll
    for (int r = 0; r < 4; ++r)
      gld16(A + (long)(r * 32 + srow) * IS_DIM + k0 + scolsw,
            sA + (r * 32 + srow) * 64 + scol);
    #pragma unroll
    for (int r = 0; r < 2; ++r)
      gld16(B + (long)(r * 32 + srow) * K_TOT + k0 + scolsw,
            sB + (r * 32 + srow) * 64 + scol);
    __syncthreads();
    #pragma unroll
    for (int kk = 0; kk < 2; ++kk) {
      const int ko = kk * 32 + lk;
      bf16x8 a[4], b[2];
      #pragma unroll
      for (int mi = 0; mi < 4; ++mi)
        a[mi] = *(const bf16x8*)(sA + (wm * 64 + mi * 16 + l15) * 64 + (ko ^ ksw));
      #pragma unroll
      for (int ni = 0; ni < 2; ++ni)
        b[ni] = *(const bf16x8*)(sB + (wn * 32 + ni * 16 + l15) * 64 + (ko ^ ksw));
      #pragma unroll
      for (int mi = 0; mi < 4; ++mi)
        #pragma unroll
        for (int ni = 0; ni < 2; ++ni)
          acc[mi][ni] = __builtin_amdgcn_mfma_f32_16x16x32_bf16(a[mi], b[ni], acc[mi][ni], 0, 0, 0);
    }
    __syncthreads();
  }

  #pragma unroll
  for (int mi = 0; mi < 4; ++mi) {
    #pragma unroll
    for (int r = 0; r < 4; ++r) {
      const int t = t0 + wm * 64 + mi * 16 + (lane >> 4) * 4 + r;
      #pragma unroll
      for (int ni = 0; ni < 2; ++ni)
        out[(long)t * H_DIM + n0 + wn * 32 + ni * 16 + l15] = acc[mi][ni][r];
    }
  }
}

// ---------------------------------------------------------------------------
// Sparse expert-down GEMM, 512 threads (8 waves), tile 128x64, 2-phase dbuf;
// atomicAdd-scatter to out[tok]. Grid (n0, tile).
// ---------------------------------------------------------------------------
__global__ __launch_bounds__(512, 4) void down_moe_kernel(
    const unsigned short* __restrict__ act,
    const unsigned short* __restrict__ wdT,
    const int* __restrict__ cnt,
    const unsigned int* __restrict__ pairs,
    const unsigned int* __restrict__ tiles,
    const int* __restrict__ ntp,
    float* __restrict__ out)
{
  const int ti = blockIdx.y;
  if (ti >= *ntp) return;
  const unsigned int tile = tiles[ti];
  const int e  = (int)(tile >> 16);
  const int m0 = (int)(tile & 0xFFFFu);
  const int cnte = cnt[e];
  const int n0 = blockIdx.x * 64;
  const unsigned short* A = act + ((long)e * SLOT_CAP + m0) * I_DIM;
  const unsigned short* B = wdT + (long)n0 * K_TOT + (long)e * I_DIM;

  __shared__ unsigned short sA[2][128 * 64];
  __shared__ unsigned short sB[2][64 * 64];

  const int tid = threadIdx.x;
  const int lane = tid & 63;
  const int wid = tid >> 6;
  const int wm = wid >> 1, wn = wid & 1;
  const int l15 = lane & 15;
  const int lk  = (lane >> 4) * 8;
  const int srow = tid >> 3;          // 0..63
  const int scol = (tid & 7) * 8;
  const int scolsw = (((tid & 7) ^ (srow & 7))) * 8;
  const int ksw = (l15 & 7) << 3;

  const f32x4 fz = {0.f, 0.f, 0.f, 0.f};
  f32x4 acc[2][2];
  #pragma unroll
  for (int i = 0; i < 2; ++i)
    #pragma unroll
    for (int j = 0; j < 2; ++j) acc[i][j] = fz;

#define STAGE_DN(buf, k0) do {                                                 \
    gld16(A + (long)srow * I_DIM + (k0) + scolsw,                              \
          sA[buf] + srow * 64 + scol);                                         \
    gld16(A + (long)(64 + srow) * I_DIM + (k0) + scolsw,                       \
          sA[buf] + (64 + srow) * 64 + scol);                                  \
    gld16(B + (long)srow * K_TOT + (k0) + scolsw,                              \
          sB[buf] + srow * 64 + scol);                                         \
  } while (0)

#define COMP_DN(buf) do {                                                      \
    _Pragma("unroll")                                                          \
    for (int kk = 0; kk < 2; ++kk) {                                           \
      const int ko = kk * 32 + lk;                                             \
      bf16x8 a[2], b[2];                                                       \
      _Pragma("unroll")                                                        \
      for (int mi = 0; mi < 2; ++mi)                                           \
        a[mi] = *(const bf16x8*)(sA[buf] + (wm * 32 + mi * 16 + l15) * 64 +    \
                                 (ko ^ ksw));                                  \
      _Pragma("unroll")                                                        \
      for (int ni = 0; ni < 2; ++ni)                                           \
        b[ni] = *(const bf16x8*)(sB[buf] + (wn * 32 + ni * 16 + l15) * 64 +    \
                                 (ko ^ ksw));                                  \
      _Pragma("unroll")                                                        \
      for (int mi = 0; mi < 2; ++mi)                                           \
        _Pragma("unroll")                                                      \
        for (int ni = 0; ni < 2; ++ni)                                         \
          acc[mi][ni] = __builtin_amdgcn_mfma_f32_16x16x32_bf16(               \
              a[mi], b[ni], acc[mi][ni], 0, 0, 0);                             \
    }                                                                          \
  } while (0)

  STAGE_DN(0, 0);
  __syncthreads();
  for (int t = 0; t < 16; t += 2) {
    if (t + 1 < 16) STAGE_DN(1, (t + 1) * 64);
    COMP_DN(0);
    __syncthreads();
    if (t + 2 < 16) STAGE_DN(0, (t + 2) * 64);
    COMP_DN(1);
    __syncthreads();
  }
#undef STAGE_DN
#undef COMP_DN

  #pragma unroll
  for (int mi = 0; mi < 2; ++mi) {
    #pragma unroll
    for (int r = 0; r < 4; ++r) {
      const int slot = m0 + wm * 32 + mi * 16 + (lane >> 4) * 4 + r;
      if (slot < cnte) {
        const int tok = (int)(pairs[e * SLOT_CAP + slot] & 0xFFFFu);
        #pragma unroll
        for (int ni = 0; ni < 2; ++ni)
          atomicAdd(out + (long)tok * H_DIM + n0 + wn * 32 + ni * 16 + l15,
                    acc[mi][ni][r]);
      }
    }
  }
}

// ---------------------------------------------------------------------------
extern "C" void kernel_launch(void* const* d_in, const int* in_sizes, int n_in,
                              void* d_out, int out_size, void* d_ws, size_t ws_size,
                              hipStream_t stream) {
  (void)in_sizes; (void)n_in; (void)out_size; (void)ws_size;
  const float* x   = (const float*)d_in[0];
  const float* gw  = (const float*)d_in[1];
  const float* wg  = (const float*)d_in[2];
  const float* wu  = (const float*)d_in[3];
  const float* wd  = (const float*)d_in[4];
  const float* wsg = (const float*)d_in[5];
  const float* wsu = (const float*)d_in[6];
  const float* wsd = (const float*)d_in[7];
  float* out = (float*)d_out;
  char* ws = (char*)d_ws;

  int*            cnt   = (int*)(ws + OFF_CNT);
  int*            ntp   = (int*)(ws + OFF_NT);
  unsigned int*   tiles = (unsigned int*)(ws + OFF_TILES);
  unsigned int*   pairs = (unsigned int*)(ws + OFF_PAIRS);
  unsigned short* xb    = (unsigned short*)(ws + OFF_XB);
  unsigned short* wgT   = (unsigned short*)(ws + OFF_WGT);
  unsigned short* wuT   = (unsigned short*)(ws + OFF_WUT);
  unsigned short* hsb   = (unsigned short*)(ws + OFF_HS);   // aliases wuT
  unsigned short* wsgT  = (unsigned short*)(ws + OFF_WSGT);
  unsigned short* wsuT  = (unsigned short*)(ws + OFF_WSUT);
  unsigned short* wdT   = (unsigned short*)(ws + OFF_WDT);
  unsigned short* actb  = (unsigned short*)(ws + OFF_ACT);

  hipMemsetAsync(ws + OFF_CNT, 0, 128, stream);

  router_kernel<<<T_TOK, 256, 0, stream>>>(x, gw, cnt, pairs);
  build_tiles_kernel<<<1, 64, 0, stream>>>(cnt, tiles, ntp);
  cvt_bf16_kernel<<<(T_TOK * H_DIM / 4 + 255) / 256, 256, 0, stream>>>(
      x, xb, T_TOK * H_DIM / 4);

  // fused transpose+cvt of all 6 weight tensors
  TDescTable td;
  // 0: wg [E][H][I] -> wgT [E][I][H]
  td.in[0] = wg;  td.out[0] = wgT;  td.C[0] = I_DIM;  td.ldout[0] = H_DIM;
  td.in_bs[0] = (long)H_DIM * I_DIM; td.out_bs[0] = (long)I_DIM * H_DIM;
  td.nbx[0] = I_DIM / 64; td.nbxy[0] = (I_DIM / 64) * (H_DIM / 64);
  // 1: wu -> wuT
  td.in[1] = wu;  td.out[1] = wuT;  td.C[1] = I_DIM;  td.ldout[1] = H_DIM;
  td.in_bs[1] = (long)H_DIM * I_DIM; td.out_bs[1] = (long)I_DIM * H_DIM;
  td.nbx[1] = I_DIM / 64; td.nbxy[1] = (I_DIM / 64) * (H_DIM / 64);
  // 2: wd [E][I][H] -> wdT cols [H][e*I..]
  td.in[2] = wd;  td.out[2] = wdT;  td.C[2] = H_DIM;  td.ldout[2] = K_TOT;
  td.in_bs[2] = (long)I_DIM * H_DIM; td.out_bs[2] = (long)I_DIM;
  td.nbx[2] = H_DIM / 64; td.nbxy[2] = (H_DIM / 64) * (I_DIM / 64);
  // 3: wsg [H][IS] -> wsgT [IS][H]
  td.in[3] = wsg; td.out[3] = wsgT; td.C[3] = IS_DIM; td.ldout[3] = H_DIM;
  td.in_bs[3] = 0; td.out_bs[3] = 0;
  td.nbx[3] = IS_DIM / 64; td.nbxy[3] = (IS_DIM / 64) * (H_DIM / 64);
  // 4: wsu -> wsuT
  td.in[4] = wsu; td.out[4] = wsuT; td.C[4] = IS_DIM; td.ldout[4] = H_DIM;
  td.in_bs[4] = 0; td.out_bs[4] = 0;
  td.nbx[4] = IS_DIM / 64; td.nbxy[4] = (IS_DIM / 64) * (H_DIM / 64);
  // 5: wsd [IS][H] -> wdT cols [H][32768..]
  td.in[5] = wsd; td.out[5] = wdT + E_NUM * I_DIM; td.C[5] = H_DIM;
  td.ldout[5] = K_TOT; td.in_bs[5] = 0; td.out_bs[5] = 0;
  td.nbx[5] = H_DIM / 64; td.nbxy[5] = (H_DIM / 64) * (IS_DIM / 64);
  td.start[0] = 0;
  for (int i = 0; i < 5; ++i) {
    int nz = (i <= 2) ? E_NUM : 1;
    td.start[i + 1] = td.start[i] + td.nbxy[i] * nz;
  }
  td.start[6] = td.start[5] + td.nbxy[5];
  transpose_fused<<<td.start[6], 256, 0, stream>>>(td);

  // sparse experts gate+up -> compact act (router weights folded in)
  gate_up_moe_kernel<<<dim3(16, MAX_TILES), 512, 0, stream>>>(
      xb, wgT, wuT, cnt, pairs, tiles, ntp, actb);

  // shared expert gate+up -> hs (aliases wuT; wuT dead after gate_up_moe)
  gate_up_shared_kernel<<<dim3(16, 32), 256, 0, stream>>>(
      xb, wsgT, wsuT, hsb);

  // shared-expert down writes out, then expert down atomic-adds
  down_shared_kernel<<<dim3(16, 32), 256, 0, stream>>>(
      hsb, wdT + E_NUM * I_DIM, out);
  down_moe_kernel<<<dim3(32, MAX_TILES), 512, 0, stream>>>(
      actb, wdT, cnt, pairs, tiles, ntp, out);
}

// Round 6
// 860.855 us; speedup vs baseline: 1.8385x; 1.0058x over previous
//
#include <hip/hip_runtime.h>

// Problem dims (fixed by the reference)
#define T_TOK 2048      // B*S tokens
#define H_DIM 2048
#define E_NUM 32
#define I_DIM 1024
#define IS_DIM 2048
#define K_TOT (E_NUM * I_DIM + IS_DIM)   // 34816
#define SLOT_CAP 2048
#define NE_ALL 34        // 32 routed + 2 shared pseudo-experts
#define GU_TILES 192     // <=159 routed + 32 shared
#define DN_TILES 176     // <=159 routed + 16 shared (K=2048)
#define ACT_SLOTS 24576  // sum pad128(cnt_e) (<=20448) + 4096 shared

typedef __bf16 bf16x8 __attribute__((ext_vector_type(8)));
typedef float  f32x4  __attribute__((ext_vector_type(4)));
static_assert(sizeof(bf16x8) == 16, "bf16x8 must be 16B");

// Workspace layout (bytes). Total = 486,819,840.
#define OFF_CNT   ((size_t)0)            // cnt[34] int
#define OFF_NTGU  ((size_t)192)
#define OFF_NTDN  ((size_t)196)
#define OFF_BASE  ((size_t)256)          // base[34] int
#define OFF_TGU   ((size_t)512)          // tilesGU[192] uint
#define OFF_TDN   ((size_t)1280)         // tilesDN[176] uint
#define OFF_PAIRS ((size_t)2048)         // pairs[34][2048] uint = 278,528
#define OFF_XB    ((size_t)280576)       // xb [T,H] bf16 = 8,388,608
#define OFF_WGT   ((size_t)8669184)      // wgT [E][I][H] bf16
#define OFF_WUT   ((size_t)142886912)    // wuT [E][I][H] bf16
#define OFF_WSGT  ((size_t)277104640)    // wsgT [IS][H] bf16
#define OFF_WSUT  ((size_t)285493248)    // wsuT [IS][H] bf16
#define OFF_WDT   ((size_t)293881856)    // wdT [H][K_TOT] bf16
#define OFF_ACT   ((size_t)436488192)    // act [24576][1024] bf16 = 50,331,648

__device__ __forceinline__ unsigned short f2bf(float f) {
  unsigned int u = __float_as_uint(f);
  u += 0x7fffu + ((u >> 16) & 1u);   // round-to-nearest-even
  return (unsigned short)(u >> 16);
}

__device__ __forceinline__ void gld16(const void* g, void* l) {
  __builtin_amdgcn_global_load_lds(
      (const __attribute__((address_space(1))) unsigned int*)g,
      (__attribute__((address_space(3))) unsigned int*)l, 16, 0, 0);
}

// ---------------------------------------------------------------------------
// Router: scores = sigmoid(x @ gw^T); top-8; renorm; *2.5 -> pair lists.
// ---------------------------------------------------------------------------
__global__ __launch_bounds__(256) void router_kernel(
    const float* __restrict__ x, const float* __restrict__ gw,
    int* __restrict__ cnt, unsigned int* __restrict__ pairs)
{
  const int t = blockIdx.x;
  __shared__ float xs[H_DIM];
  __shared__ float sc[E_NUM];
  const float4* xr = (const float4*)(x + (long)t * H_DIM);
  for (int i = threadIdx.x; i < H_DIM / 4; i += 256) ((float4*)xs)[i] = xr[i];
  __syncthreads();
  const int e = threadIdx.x >> 3, p = threadIdx.x & 7;
  const float4* ga = (const float4*)(gw + (long)e * H_DIM);
  const float4* xa = (const float4*)xs;
  float s = 0.f;
  #pragma unroll 4
  for (int i = p * 64; i < p * 64 + 64; ++i) {
    float4 a = ga[i], b = xa[i];
    s += a.x * b.x + a.y * b.y + a.z * b.z + a.w * b.w;
  }
  s += __shfl_down(s, 4, 8);
  s += __shfl_down(s, 2, 8);
  s += __shfl_down(s, 1, 8);
  if (p == 0) sc[e] = 1.f / (1.f + expf(-s));
  __syncthreads();
  if (threadIdx.x == 0) {
    float v[E_NUM];
    #pragma unroll
    for (int i = 0; i < E_NUM; ++i) v[i] = sc[i];
    unsigned mask = 0; float sum = 0.f;
    int sel[8]; float wv[8];
    for (int k = 0; k < 8; ++k) {
      float best = -1.f; int bi = 0;
      for (int i = 0; i < E_NUM; ++i)
        if (!((mask >> i) & 1u) && v[i] > best) { best = v[i]; bi = i; }
      mask |= 1u << bi; sel[k] = bi; wv[k] = best; sum += best;
    }
    const float scale = 2.5f / (sum + 1e-20f);
    for (int k = 0; k < 8; ++k) {
      const int slot = atomicAdd(&cnt[sel[k]], 1);
      if (slot < SLOT_CAP) {
        const unsigned int w16 = (unsigned int)f2bf(wv[k] * scale);
        pairs[sel[k] * SLOT_CAP + slot] = (w16 << 16) | (unsigned int)t;
      }
    }
  }
}

// ---------------------------------------------------------------------------
// Build tile lists + per-expert act bases; fill shared pseudo-expert pairs.
// GU list: e 0..33 (shared as two 1024-wide panels). DN list: e 0..32
// (e=32 tiles run K=2048, consuming both shared act panels).
// ---------------------------------------------------------------------------
__global__ __launch_bounds__(256) void build_tiles_kernel(
    int* __restrict__ cnt, int* __restrict__ base,
    unsigned int* __restrict__ tgu, int* __restrict__ ntgu,
    unsigned int* __restrict__ tdn, int* __restrict__ ntdn,
    unsigned int* __restrict__ pairs)
{
  const int t = threadIdx.x;
  for (int s = t; s < T_TOK; s += 256) {
    const unsigned int pv = (0x3F80u << 16) | (unsigned int)s;  // w=1.0 bf16
    pairs[32 * SLOT_CAP + s] = pv;
    pairs[33 * SLOT_CAP + s] = pv;
  }
  if (t == 0) {
    cnt[32] = T_TOK; cnt[33] = T_TOK;
    int b = 0, ngu = 0, ndn = 0;
    for (int e = 0; e < NE_ALL; ++e) {
      const int c = (e < 32) ? cnt[e] : T_TOK;
      base[e] = b;
      for (int m0 = 0; m0 < c; m0 += 128) {
        tgu[ngu++] = ((unsigned int)e << 16) | (unsigned int)m0;
        if (e < 33) tdn[ndn++] = ((unsigned int)e << 16) | (unsigned int)m0;
      }
      b += (c + 127) & ~127;
    }
    *ntgu = ngu; *ntdn = ndn;
  }
}

// ---------------------------------------------------------------------------
__global__ __launch_bounds__(256) void cvt_bf16_kernel(
    const float* __restrict__ in, unsigned short* __restrict__ out, int n4)
{
  int i = blockIdx.x * 256 + threadIdx.x;
  if (i >= n4) return;
  float4 v = ((const float4*)in)[i];
  ushort4 o;
  o.x = f2bf(v.x); o.y = f2bf(v.y); o.z = f2bf(v.z); o.w = f2bf(v.w);
  ((ushort4*)out)[i] = o;
}

// ---------------------------------------------------------------------------
// Fused transpose+cvt, 64(c) x 256(r) tiles, bf16 in LDS (ld=258: 2-way-free
// scalar writes), 16B uint4 stores -> 512B-contiguous output segments.
// ---------------------------------------------------------------------------
struct TDescTable {
  const float* in[6];
  unsigned short* out[6];
  int C[6];
  int ldout[6];
  long in_bs[6];
  long out_bs[6];
  int nbx[6];
  int nbxy[6];
  int start[7];
};

__global__ __launch_bounds__(256) void transpose_fused(TDescTable td)
{
  const int bid = blockIdx.x;
  int i = 0;
  while (i < 5 && bid >= td.start[i + 1]) ++i;
  const int local = bid - td.start[i];
  const int bz = local / td.nbxy[i];
  const int rem = local % td.nbxy[i];
  const int by = rem / td.nbx[i];
  const int bx = rem % td.nbx[i];
  const float* in = td.in[i] + (long)bz * td.in_bs[i];
  unsigned short* out = td.out[i] + (long)bz * td.out_bs[i];
  const int C = td.C[i], ldout = td.ldout[i];

  __shared__ unsigned short tile[64][258];
  const int c0 = bx * 64;
  const int r0 = by * 256;
  const int t = threadIdx.x;
  const int rl0 = t >> 4;          // 0..15
  const int cl0 = (t & 15) * 4;    // 0..60
  #pragma unroll
  for (int p = 0; p < 16; ++p) {
    const int rl = p * 16 + rl0;
    float4 v = *(const float4*)(in + (long)(r0 + rl) * C + c0 + cl0);
    tile[cl0 + 0][rl] = f2bf(v.x);
    tile[cl0 + 1][rl] = f2bf(v.y);
    tile[cl0 + 2][rl] = f2bf(v.z);
    tile[cl0 + 3][rl] = f2bf(v.w);
  }
  __syncthreads();
  const int cw = t >> 5;           // 0..7
  const int rw = (t & 31) * 8;     // 0..248
  #pragma unroll
  for (int q = 0; q < 8; ++q) {
    const int cl = q * 8 + cw;
    const char* src = (const char*)&tile[cl][rw];  // 4B-aligned
    uint4 o;
    o.x = *(const unsigned int*)(src + 0);
    o.y = *(const unsigned int*)(src + 4);
    o.z = *(const unsigned int*)(src + 8);
    o.w = *(const unsigned int*)(src + 12);
    *(uint4*)(out + (long)(c0 + cl) * ldout + r0 + rw) = o;
  }
}

// ---------------------------------------------------------------------------
// Unified gate+up GEMM over GU tile list (routed + shared pseudo-experts),
// 512 thr (8 waves), tile 128x64, BK=64, 2-phase dbuf, XOR-swizzled LDS,
// gathered A rows; writes compact act[(base[e]+slot)][I].
// ---------------------------------------------------------------------------
__global__ __launch_bounds__(512, 4) void gate_up_moe_kernel(
    const unsigned short* __restrict__ xb,
    const unsigned short* __restrict__ bgT,
    const unsigned short* __restrict__ buT,
    const unsigned short* __restrict__ sgT,
    const unsigned short* __restrict__ suT,
    const int* __restrict__ cnt,
    const int* __restrict__ base,
    const unsigned int* __restrict__ pairs,
    const unsigned int* __restrict__ tiles,
    const int* __restrict__ ntp,
    unsigned short* __restrict__ act)
{
  const int ti = blockIdx.y;
  if (ti >= *ntp) return;
  const unsigned int tile = tiles[ti];
  const int e  = (int)(tile >> 16);
  const int m0 = (int)(tile & 0xFFFFu);
  const int cnte = cnt[e];
  const int be = base[e];
  const int n0 = blockIdx.x * 64;
  const long panel = (long)I_DIM * H_DIM;
  const unsigned short* Bg =
      ((e < 32) ? bgT + e * panel : sgT + (e - 32) * panel) + (long)n0 * H_DIM;
  const unsigned short* Bu =
      ((e < 32) ? buT + e * panel : suT + (e - 32) * panel) + (long)n0 * H_DIM;

  __shared__ unsigned short sA[2][128 * 64];
  __shared__ unsigned short sBg[2][64 * 64];
  __shared__ unsigned short sBu[2][64 * 64];

  const int tid = threadIdx.x;
  const int lane = tid & 63;
  const int wid = tid >> 6;
  const int wm = wid >> 1, wn = wid & 1;
  const int l15 = lane & 15;
  const int lk  = (lane >> 4) * 8;
  const int srow = tid >> 3;          // 0..63
  const int scol = (tid & 7) * 8;
  const int scolsw = (((tid & 7) ^ (srow & 7))) * 8;
  const int ksw = (l15 & 7) << 3;

  const unsigned short* asrc[2];
  #pragma unroll
  for (int r = 0; r < 2; ++r) {
    const int slot = m0 + r * 64 + srow;
    const unsigned int pr = (slot < cnte) ? pairs[e * SLOT_CAP + slot] : 0u;
    asrc[r] = xb + (long)(pr & 0xFFFFu) * H_DIM + scolsw;
  }

  const f32x4 fz = {0.f, 0.f, 0.f, 0.f};
  f32x4 accg[2][2], accu[2][2];
  #pragma unroll
  for (int i = 0; i < 2; ++i)
    #pragma unroll
    for (int j = 0; j < 2; ++j) { accg[i][j] = fz; accu[i][j] = fz; }

#define STAGE_GU(buf, k0) do {                                                 \
    gld16(asrc[0] + (k0), sA[buf] + srow * 64 + scol);                         \
    gld16(asrc[1] + (k0), sA[buf] + (64 + srow) * 64 + scol);                  \
    gld16(Bg + (long)srow * H_DIM + (k0) + scolsw,                             \
          sBg[buf] + srow * 64 + scol);                                        \
    gld16(Bu + (long)srow * H_DIM + (k0) + scolsw,                             \
          sBu[buf] + srow * 64 + scol);                                        \
  } while (0)

#define COMP_GU(buf) do {                                                      \
    _Pragma("unroll")                                                          \
    for (int kk = 0; kk < 2; ++kk) {                                           \
      const int ko = kk * 32 + lk;                                             \
      bf16x8 a[2], g[2], u[2];                                                 \
      _Pragma("unroll")                                                        \
      for (int mi = 0; mi < 2; ++mi)                                           \
        a[mi] = *(const bf16x8*)(sA[buf] + (wm * 32 + mi * 16 + l15) * 64 +    \
                                 (ko ^ ksw));                                  \
      _Pragma("unroll")                                                        \
      for (int ni = 0; ni < 2; ++ni) {                                         \
        g[ni] = *(const bf16x8*)(sBg[buf] + (wn * 32 + ni * 16 + l15) * 64 +   \
                                 (ko ^ ksw));                                  \
        u[ni] = *(const bf16x8*)(sBu[buf] + (wn * 32 + ni * 16 + l15) * 64 +   \
                                 (ko ^ ksw));                                  \
      }                                                                        \
      _Pragma("unroll")                                                        \
      for (int mi = 0; mi < 2; ++mi)                                           \
        _Pragma("unroll")                                                      \
        for (int ni = 0; ni < 2; ++ni) {                                       \
          accg[mi][ni] = __builtin_amdgcn_mfma_f32_16x16x32_bf16(              \
              a[mi], g[ni], accg[mi][ni], 0, 0, 0);                            \
          accu[mi][ni] = __builtin_amdgcn_mfma_f32_16x16x32_bf16(              \
              a[mi], u[ni], accu[mi][ni], 0, 0, 0);                            \
        }                                                                      \
    }                                                                          \
  } while (0)

  STAGE_GU(0, 0);
  __syncthreads();
  for (int t = 0; t < 32; t += 2) {
    if (t + 1 < 32) STAGE_GU(1, (t + 1) * 64);
    COMP_GU(0);
    __syncthreads();
    if (t + 2 < 32) STAGE_GU(0, (t + 2) * 64);
    COMP_GU(1);
    __syncthreads();
  }
#undef STAGE_GU
#undef COMP_GU

  const int colb = n0 + wn * 32;
  #pragma unroll
  for (int mi = 0; mi < 2; ++mi) {
    #pragma unroll
    for (int r = 0; r < 4; ++r) {
      const int slot = m0 + wm * 32 + mi * 16 + (lane >> 4) * 4 + r;
      if (slot < cnte) {
        const unsigned int pr = pairs[e * SLOT_CAP + slot];
        const float w = __uint_as_float(pr & 0xFFFF0000u);
        #pragma unroll
        for (int ni = 0; ni < 2; ++ni) {
          const float gv = accg[mi][ni][r];
          const float uv = accu[mi][ni][r];
          const float sv = (gv / (1.f + expf(-gv))) * uv * w;
          act[((long)(be + slot)) * I_DIM + colb + ni * 16 + l15] = f2bf(sv);
        }
      }
    }
  }
}

// ---------------------------------------------------------------------------
// Unified down GEMM over DN tile list; e=32 runs K=2048 spanning both shared
// act panels (base33 = base32 + 2048). atomicAdd-scatter onto zeroed out.
// 512 thr, tile 128x64, 2-phase dbuf, XOR-swizzled LDS.
// ---------------------------------------------------------------------------
__global__ __launch_bounds__(512, 4) void down_moe_kernel(
    const unsigned short* __restrict__ act,
    const unsigned short* __restrict__ wdT,
    const int* __restrict__ cnt,
    const int* __restrict__ base,
    const unsigned int* __restrict__ pairs,
    const unsigned int* __restrict__ tiles,
    const int* __restrict__ ntp,
    float* __restrict__ out)
{
  const int ti = blockIdx.y;
  if (ti >= *ntp) return;
  const unsigned int tile = tiles[ti];
  const int e  = (int)(tile >> 16);
  const int m0 = (int)(tile & 0xFFFFu);
  const int cnte = cnt[e];
  const int n0 = blockIdx.x * 64;
  const unsigned short* A = act + ((long)base[e] + m0) * I_DIM;
  const unsigned short* B = wdT + (long)n0 * K_TOT + (long)e * I_DIM;
  const int nk = (e == 32) ? 32 : 16;   // K-steps of 64

  __shared__ unsigned short sA[2][128 * 64];
  __shared__ unsigned short sB[2][64 * 64];

  const int tid = threadIdx.x;
  const int lane = tid & 63;
  const int wid = tid >> 6;
  const int wm = wid >> 1, wn = wid & 1;
  const int l15 = lane & 15;
  const int lk  = (lane >> 4) * 8;
  const int srow = tid >> 3;
  const int scol = (tid & 7) * 8;
  const int scolsw = (((tid & 7) ^ (srow & 7))) * 8;
  const int ksw = (l15 & 7) << 3;

  const f32x4 fz = {0.f, 0.f, 0.f, 0.f};
  f32x4 acc[2][2];
  #pragma unroll
  for (int i = 0; i < 2; ++i)
    #pragma unroll
    for (int j = 0; j < 2; ++j) acc[i][j] = fz;

#define STAGE_DN(buf, k0) do {                                                 \
    const long koff = (long)((k0) & 1023) +                                    \
                      (long)((k0) >> 10) * (2048L * 1024L);                    \
    gld16(A + (long)srow * I_DIM + koff + scolsw,                              \
          sA[buf] + srow * 64 + scol);                                         \
    gld16(A + (long)(64 + srow) * I_DIM + koff + scolsw,                       \
          sA[buf] + (64 + srow) * 64 + scol);                                  \
    gld16(B + (long)srow * K_TOT + (k0) + scolsw,                              \
          sB[buf] + srow * 64 + scol);                                         \
  } while (0)

#define COMP_DN(buf) do {                                                      \
    _Pragma("unroll")                                                          \
    for (int kk = 0; kk < 2; ++kk) {                                           \
      const int ko = kk * 32 + lk;                                             \
      bf16x8 a[2], b[2];                                                       \
      _Pragma("unroll")                                                        \
      for (int mi = 0; mi < 2; ++mi)                                           \
        a[mi] = *(const bf16x8*)(sA[buf] + (wm * 32 + mi * 16 + l15) * 64 +    \
                                 (ko ^ ksw));                                  \
      _Pragma("unroll")                                                        \
      for (int ni = 0; ni < 2; ++ni)                                           \
        b[ni] = *(const bf16x8*)(sB[buf] + (wn * 32 + ni * 16 + l15) * 64 +    \
                                 (ko ^ ksw));                                  \
      _Pragma("unroll")                                                        \
      for (int mi = 0; mi < 2; ++mi)                                           \
        _Pragma("unroll")                                                      \
        for (int ni = 0; ni < 2; ++ni)                                         \
          acc[mi][ni] = __builtin_amdgcn_mfma_f32_16x16x32_bf16(               \
              a[mi], b[ni], acc[mi][ni], 0, 0, 0);                             \
    }                                                                          \
  } while (0)

  STAGE_DN(0, 0);
  __syncthreads();
  for (int t = 0; t < nk; t += 2) {
    if (t + 1 < nk) STAGE_DN(1, (t + 1) * 64);
    COMP_DN(0);
    __syncthreads();
    if (t + 2 < nk) STAGE_DN(0, (t + 2) * 64);
    COMP_DN(1);
    __syncthreads();
  }
#undef STAGE_DN
#undef COMP_DN

  #pragma unroll
  for (int mi = 0; mi < 2; ++mi) {
    #pragma unroll
    for (int r = 0; r < 4; ++r) {
      const int slot = m0 + wm * 32 + mi * 16 + (lane >> 4) * 4 + r;
      if (slot < cnte) {
        const int tok = (int)(pairs[e * SLOT_CAP + slot] & 0xFFFFu);
        #pragma unroll
        for (int ni = 0; ni < 2; ++ni)
          atomicAdd(out + (long)tok * H_DIM + n0 + wn * 32 + ni * 16 + l15,
                    acc[mi][ni][r]);
      }
    }
  }
}

// ---------------------------------------------------------------------------
extern "C" void kernel_launch(void* const* d_in, const int* in_sizes, int n_in,
                              void* d_out, int out_size, void* d_ws, size_t ws_size,
                              hipStream_t stream) {
  (void)in_sizes; (void)n_in; (void)ws_size;
  const float* x   = (const float*)d_in[0];
  const float* gw  = (const float*)d_in[1];
  const float* wg  = (const float*)d_in[2];
  const float* wu  = (const float*)d_in[3];
  const float* wd  = (const float*)d_in[4];
  const float* wsg = (const float*)d_in[5];
  const float* wsu = (const float*)d_in[6];
  const float* wsd = (const float*)d_in[7];
  float* out = (float*)d_out;
  char* ws = (char*)d_ws;

  int*            cnt   = (int*)(ws + OFF_CNT);
  int*            ntgu  = (int*)(ws + OFF_NTGU);
  int*            ntdn  = (int*)(ws + OFF_NTDN);
  int*            basep = (int*)(ws + OFF_BASE);
  unsigned int*   tgu   = (unsigned int*)(ws + OFF_TGU);
  unsigned int*   tdn   = (unsigned int*)(ws + OFF_TDN);
  unsigned int*   pairs = (unsigned int*)(ws + OFF_PAIRS);
  unsigned short* xb    = (unsigned short*)(ws + OFF_XB);
  unsigned short* wgT   = (unsigned short*)(ws + OFF_WGT);
  unsigned short* wuT   = (unsigned short*)(ws + OFF_WUT);
  unsigned short* wsgT  = (unsigned short*)(ws + OFF_WSGT);
  unsigned short* wsuT  = (unsigned short*)(ws + OFF_WSUT);
  unsigned short* wdT   = (unsigned short*)(ws + OFF_WDT);
  unsigned short* actb  = (unsigned short*)(ws + OFF_ACT);

  hipMemsetAsync(ws + OFF_CNT, 0, 256, stream);           // cnt + nt
  hipMemsetAsync(out, 0, (size_t)out_size * sizeof(float), stream);

  router_kernel<<<T_TOK, 256, 0, stream>>>(x, gw, cnt, pairs);
  build_tiles_kernel<<<1, 256, 0, stream>>>(cnt, basep, tgu, ntgu, tdn, ntdn,
                                            pairs);
  cvt_bf16_kernel<<<(T_TOK * H_DIM / 4 + 255) / 256, 256, 0, stream>>>(
      x, xb, T_TOK * H_DIM / 4);

  // fused transpose+cvt of all 6 weight tensors (64c x 256r tiles)
  TDescTable td;
  // 0: wg [E][H][I] -> wgT [E][I][H]   (R=H=2048, C=I=1024)
  td.in[0] = wg;  td.out[0] = wgT;  td.C[0] = I_DIM;  td.ldout[0] = H_DIM;
  td.in_bs[0] = (long)H_DIM * I_DIM; td.out_bs[0] = (long)I_DIM * H_DIM;
  td.nbx[0] = I_DIM / 64; td.nbxy[0] = (I_DIM / 64) * (H_DIM / 256);
  // 1: wu -> wuT
  td.in[1] = wu;  td.out[1] = wuT;  td.C[1] = I_DIM;  td.ldout[1] = H_DIM;
  td.in_bs[1] = (long)H_DIM * I_DIM; td.out_bs[1] = (long)I_DIM * H_DIM;
  td.nbx[1] = I_DIM / 64; td.nbxy[1] = (I_DIM / 64) * (H_DIM / 256);
  // 2: wd [E][I][H] -> wdT cols [H][e*I..]   (R=I=1024, C=H=2048)
  td.in[2] = wd;  td.out[2] = wdT;  td.C[2] = H_DIM;  td.ldout[2] = K_TOT;
  td.in_bs[2] = (long)I_DIM * H_DIM; td.out_bs[2] = (long)I_DIM;
  td.nbx[2] = H_DIM / 64; td.nbxy[2] = (H_DIM / 64) * (I_DIM / 256);
  // 3: wsg [H][IS] -> wsgT [IS][H]
  td.in[3] = wsg; td.out[3] = wsgT; td.C[3] = IS_DIM; td.ldout[3] = H_DIM;
  td.in_bs[3] = 0; td.out_bs[3] = 0;
  td.nbx[3] = IS_DIM / 64; td.nbxy[3] = (IS_DIM / 64) * (H_DIM / 256);
  // 4: wsu -> wsuT
  td.in[4] = wsu; td.out[4] = wsuT; td.C[4] = IS_DIM; td.ldout[4] = H_DIM;
  td.in_bs[4] = 0; td.out_bs[4] = 0;
  td.nbx[4] = IS_DIM / 64; td.nbxy[4] = (IS_DIM / 64) * (H_DIM / 256);
  // 5: wsd [IS][H] -> wdT cols [H][32768..]
  td.in[5] = wsd; td.out[5] = wdT + E_NUM * I_DIM; td.C[5] = H_DIM;
  td.ldout[5] = K_TOT; td.in_bs[5] = 0; td.out_bs[5] = 0;
  td.nbx[5] = H_DIM / 64; td.nbxy[5] = (H_DIM / 64) * (IS_DIM / 256);
  td.start[0] = 0;
  for (int i = 0; i < 5; ++i) {
    int nz = (i <= 2) ? E_NUM : 1;
    td.start[i + 1] = td.start[i] + td.nbxy[i] * nz;
  }
  td.start[6] = td.start[5] + td.nbxy[5];
  transpose_fused<<<td.start[6], 256, 0, stream>>>(td);

  // unified gate+up (routed + shared pseudo-experts) -> compact act
  gate_up_moe_kernel<<<dim3(16, GU_TILES), 512, 0, stream>>>(
      xb, wgT, wuT, wsgT, wsuT, cnt, basep, pairs, tgu, ntgu, actb);

  // unified down (routed K=1024, shared K=2048) -> atomicAdd onto zeroed out
  down_moe_kernel<<<dim3(32, DN_TILES), 512, 0, stream>>>(
      actb, wdT, cnt, basep, pairs, tdn, ntdn, out);
}